// Round 1
// baseline (2170.450 us; speedup 1.0000x reference)
//
#include <hip/hip_runtime.h>
#include <hip/hip_bf16.h>
#include <cstdint>

#define P_ 88   // pitches (sequence length of the scan)
#define B_ 16   // batch
#define T_ 256  // timesteps (folded into batch N)
#define H_ 188  // per-pitch features
#define G_ 192  // 4*48 gates; also LSTM1 input size (188 feat + 4 ctx)
#define U_ 48   // LSTM units
#define N_ 4096 // B_*T_

__device__ __forceinline__ float sigf(float x) {
  return __builtin_amdgcn_rcpf(1.0f + __expf(-x));
}
__device__ __forceinline__ float tanh_f(float x) {
  return 2.0f * sigf(2.0f * x) - 1.0f;
}

__device__ __forceinline__ float toF(float x) { return x; }
__device__ __forceinline__ float toF(__hip_bfloat16 x) { return __bfloat162float(x); }
__device__ __forceinline__ void stF(float* p, float v) { *p = v; }
__device__ __forceinline__ void stF(__hip_bfloat16* p, float v) { *p = __float2bfloat16(v); }

// ---------------------------------------------------------------------------
// Kernel 1: context MLP -> per-(b,p) gate bias vector
// ctxg[bp][g] = bih1[g] + bhh1[g] + sum_j ce[j] * wih1[g][188+j]
// ---------------------------------------------------------------------------
__global__ void ctx_kernel(const float* __restrict__ pc,
                           const float* __restrict__ fc1w, const float* __restrict__ fc1b,
                           const float* __restrict__ fc2w, const float* __restrict__ fc2b,
                           const float* __restrict__ fc3w, const float* __restrict__ fc3b,
                           const float* __restrict__ wih1,
                           const float* __restrict__ bih1, const float* __restrict__ bhh1,
                           float* __restrict__ ctxg) {
  int bp = blockIdx.x * 64 + threadIdx.x;
  if (bp >= B_ * P_) return;
  float p0 = pc[bp * 3 + 0], p1 = pc[bp * 3 + 1], p2 = pc[bp * 3 + 2];
  float x1[16], x2[16];
#pragma unroll
  for (int jj = 0; jj < 16; ++jj)
    x1[jj] = fmaxf(0.f, fc1w[jj * 3 + 0] * p0 + fc1w[jj * 3 + 1] * p1 + fc1w[jj * 3 + 2] * p2 + fc1b[jj]);
#pragma unroll
  for (int jj = 0; jj < 16; ++jj) {
    float s = fc2b[jj];
#pragma unroll
    for (int i = 0; i < 16; ++i) s += fc2w[jj * 16 + i] * x1[i];
    x2[jj] = fmaxf(0.f, s);
  }
  float ce[4];
#pragma unroll
  for (int jj = 0; jj < 4; ++jj) {
    float s = fc3b[jj];
#pragma unroll
    for (int i = 0; i < 16; ++i) s += fc3w[jj * 16 + i] * x2[i];
    ce[jj] = s;
  }
  float* op = ctxg + (size_t)bp * G_;
  for (int g = 0; g < G_; ++g) {
    const float* wr = wih1 + (size_t)g * G_ + H_;
    op[g] = bih1[g] + bhh1[g] + ce[0] * wr[0] + ce[1] * wr[1] + ce[2] * wr[2] + ce[3] * wr[3];
  }
}

// ---------------------------------------------------------------------------
// Kernel 2: xg[p][n][g] = sum_h pf[b,p,h,t] * wih1[g][h] + ctxg[bp][g]
// Block: (tB, b, p) computes a 128t x 192g tile, K=188 chunked by 16.
// Thread tile 8t x 12g (96 accs). fp32 VALU GEMM (no fp32 MFMA on CDNA4).
// ---------------------------------------------------------------------------
template <typename XT>
__global__ __launch_bounds__(256) void gemm_kernel(const float* __restrict__ pf,
                                                   const float* __restrict__ wih1,
                                                   const float* __restrict__ ctxg,
                                                   XT* __restrict__ xg) {
  const int tB = blockIdx.x, b = blockIdx.y, p = blockIdx.z;
  const int tid = threadIdx.x;
  __shared__ __align__(16) float Als[16][128];  // A chunk: [hh][t]
  __shared__ __align__(16) float Wls[16][196];  // W chunk transposed: [hh][g], padded row
  const int gtile = tid & 15, ttile = tid >> 4;
  const int t0 = ttile * 8, g0 = gtile * 12;
  float acc[8][12];
#pragma unroll
  for (int i = 0; i < 8; ++i)
#pragma unroll
    for (int j2 = 0; j2 < 12; ++j2) acc[i][j2] = 0.f;
  const float* Ab = pf + ((size_t)(b * P_ + p) * H_) * T_ + tB * 128;
  for (int kc = 0; kc < 12; ++kc) {
    const int h0 = kc * 16;
    const int kk = (kc < 11) ? 16 : 12;  // 188 = 11*16 + 12
    __syncthreads();
#pragma unroll
    for (int r = 0; r < 8; ++r) {
      int idx = r * 256 + tid, hh = idx >> 7, t = idx & 127;
      if (hh < kk) Als[hh][t] = Ab[(size_t)(h0 + hh) * T_ + t];
    }
#pragma unroll
    for (int r = 0; r < 12; ++r) {
      int idx = r * 256 + tid, hh = idx & 15, g = idx >> 4;
      if (hh < kk) Wls[hh][g] = wih1[(size_t)g * G_ + h0 + hh];
    }
    __syncthreads();
    for (int hh = 0; hh < kk; ++hh) {
      float a[8], w[12];
      *(float4*)&a[0] = *(const float4*)&Als[hh][t0];
      *(float4*)&a[4] = *(const float4*)&Als[hh][t0 + 4];
      *(float4*)&w[0] = *(const float4*)&Wls[hh][g0];
      *(float4*)&w[4] = *(const float4*)&Wls[hh][g0 + 4];
      *(float4*)&w[8] = *(const float4*)&Wls[hh][g0 + 8];
#pragma unroll
      for (int i = 0; i < 8; ++i)
#pragma unroll
        for (int j2 = 0; j2 < 12; ++j2) acc[i][j2] += a[i] * w[j2];
    }
  }
  float cg[12];
  const float* cb = ctxg + ((size_t)b * P_ + p) * G_ + g0;
#pragma unroll
  for (int j2 = 0; j2 < 12; ++j2) cg[j2] = cb[j2];
  XT* ob = xg + ((size_t)p * N_ + (size_t)b * T_ + tB * 128 + t0) * G_ + g0;
#pragma unroll
  for (int i = 0; i < 8; ++i)
#pragma unroll
    for (int j2 = 0; j2 < 12; ++j2) stF(ob + (size_t)i * G_ + j2, acc[i][j2] + cg[j2]);
}

// ---------------------------------------------------------------------------
// Kernel 3: persistent 2-layer LSTM scan over p=0..87 + fc_states + softmax.
// Block owns NB=16 batch rows (n0 = blk*16) for all 88 steps. 256 threads:
//   threads 0..191  : gate/update work (one gate id j, or 4 (u,n) update tasks)
//   threads 192..255: previous step's logits/softmax/store (overlapped)
// Weights transposed in dynamic LDS; h1/h2 in LDS (h12T[96][16]); c in regs.
// ---------------------------------------------------------------------------
#define FMA16(W, BASE)                                                        \
  {                                                                           \
    const float4* hp_ = (const float4*)(BASE);                                \
    float4 ha = hp_[0], hb = hp_[1], hc = hp_[2], hd = hp_[3];                \
    acc[0] += (W) * ha.x;  acc[1] += (W) * ha.y;  acc[2] += (W) * ha.z;  acc[3] += (W) * ha.w;  \
    acc[4] += (W) * hb.x;  acc[5] += (W) * hb.y;  acc[6] += (W) * hb.z;  acc[7] += (W) * hb.w;  \
    acc[8] += (W) * hc.x;  acc[9] += (W) * hc.y;  acc[10] += (W) * hc.z; acc[11] += (W) * hc.w; \
    acc[12] += (W) * hd.x; acc[13] += (W) * hd.y; acc[14] += (W) * hd.z; acc[15] += (W) * hd.w; \
  }

template <typename XT>
__global__ __launch_bounds__(256) void scan_kernel(const XT* __restrict__ xg,
    const float* __restrict__ whh1, const float* __restrict__ wih2,
    const float* __restrict__ whh2, const float* __restrict__ bih2,
    const float* __restrict__ bhh2, const float* __restrict__ fcw,
    const float* __restrict__ fcb, float* __restrict__ out) {
  extern __shared__ float smem[];
  float* whh1T  = smem;                  // [48][192]
  float* wcatT  = whh1T + U_ * G_;       // [96][192] (wih2 rows 0..47, whh2 rows 48..95)
  float* h12T   = wcatT + 2 * U_ * G_;   // [96][16]  (h1 rows 0..47, h2 rows 48..95)
  float* bias2s = h12T + 96 * 16;        // [192]
  float* gs     = bias2s + G_;           // [16][196] gate staging (shared by layer1/2)
  float* fcws   = gs + 16 * 196;         // [5][48]
  float* fcbs   = fcws + 5 * U_;         // [8]
  float* logit_s = fcbs + 8;             // [5][16]
  float* prob_s  = logit_s + 80;         // [5][16]

  const int tid = threadIdx.x;
  const int n0 = blockIdx.x * 16;
  const int b = n0 >> 8;
  const int t0 = n0 & 255;

  // ---- stage weights (transposed: gate index contiguous) ----
  for (int e = tid; e < G_ * U_; e += 256) {
    int jj = e / U_, u = e % U_;
    whh1T[u * G_ + jj] = whh1[e];
    wcatT[u * G_ + jj] = wih2[e];
    wcatT[(U_ + u) * G_ + jj] = whh2[e];
  }
  for (int e = tid; e < G_; e += 256) bias2s[e] = bih2[e] + bhh2[e];
  for (int e = tid; e < 5 * U_; e += 256) fcws[e] = fcw[e];
  if (tid < 5) fcbs[tid] = fcb[tid];
  for (int e = tid; e < 96 * 16; e += 256) h12T[e] = 0.f;
  __syncthreads();

  float c1[4] = {0.f, 0.f, 0.f, 0.f}, c2[4] = {0.f, 0.f, 0.f, 0.f};
  float xpre[16];
  const int j = tid;
  if (j < G_) {
    const XT* xb = xg + (size_t)n0 * G_ + j;
#pragma unroll
    for (int n = 0; n < 16; ++n) xpre[n] = toF(xb[n * G_]);
  }

  for (int p = 0; p < P_; ++p) {
    // ---- phase 1: layer-1 gates | prev-step fc_states logits ----
    if (j < G_) {
      float acc[16];
#pragma unroll
      for (int n = 0; n < 16; ++n) acc[n] = xpre[n];
      if (p > 0) {
        for (int u = 0; u < U_; ++u) {
          float w = whh1T[u * G_ + j];
          FMA16(w, h12T + u * 16);
        }
      }
#pragma unroll
      for (int n = 0; n < 16; ++n) gs[n * 196 + j] = acc[n];
    } else if (p > 0) {
      const int i = j - G_;
      for (int task = i; task < 80; task += 64) {
        int k = task >> 4, n = task & 15;
        float a = fcbs[k];
        for (int u = 0; u < U_; ++u) a += fcws[k * U_ + u] * h12T[(U_ + u) * 16 + n];
        logit_s[k * 16 + n] = a;
      }
    }
    __syncthreads();
    // ---- phase 2: layer-1 state update | prev-step softmax ----
    if (j < G_) {
#pragma unroll
      for (int r = 0; r < 4; ++r) {
        int task = r * G_ + j, u = task >> 4, n = task & 15;
        float ig = gs[n * 196 + u],          fg = gs[n * 196 + U_ + u];
        float gg = gs[n * 196 + 2 * U_ + u], og = gs[n * 196 + 3 * U_ + u];
        float cc = sigf(fg) * c1[r] + sigf(ig) * tanh_f(gg);
        c1[r] = cc;
        h12T[u * 16 + n] = sigf(og) * tanh_f(cc);
      }
    } else if (p > 0 && j < G_ + 16) {
      int n = j - G_;
      float l0 = logit_s[0 * 16 + n], l1 = logit_s[1 * 16 + n], l2 = logit_s[2 * 16 + n],
            l3 = logit_s[3 * 16 + n], l4 = logit_s[4 * 16 + n];
      float m = fmaxf(fmaxf(fmaxf(l0, l1), fmaxf(l2, l3)), l4);
      float e0 = __expf(l0 - m), e1 = __expf(l1 - m), e2 = __expf(l2 - m),
            e3 = __expf(l3 - m), e4 = __expf(l4 - m);
      float rs = __builtin_amdgcn_rcpf(e0 + e1 + e2 + e3 + e4);
      prob_s[0 * 16 + n] = e0 * rs; prob_s[1 * 16 + n] = e1 * rs;
      prob_s[2 * 16 + n] = e2 * rs; prob_s[3 * 16 + n] = e3 * rs;
      prob_s[4 * 16 + n] = e4 * rs;
    }
    __syncthreads();
    // ---- phase 3: layer-2 gates (+ prefetch next xg) | prev-step store ----
    if (j < G_) {
      if (p < P_ - 1) {  // issue next-step loads early; latency hides under the K=96 loop
        const XT* xb = xg + ((size_t)(p + 1) * N_ + n0) * G_ + j;
#pragma unroll
        for (int n = 0; n < 16; ++n) xpre[n] = toF(xb[n * G_]);
      }
      float acc[16];
      float bz = bias2s[j];
#pragma unroll
      for (int n = 0; n < 16; ++n) acc[n] = bz;
      for (int u = 0; u < 2 * U_; ++u) {  // K=96: [h1; h2] against [wih2; whh2]
        float w = wcatT[u * G_ + j];
        FMA16(w, h12T + u * 16);
      }
#pragma unroll
      for (int n = 0; n < 16; ++n) gs[n * 196 + j] = acc[n];
    } else if (p > 0) {
      const int i = j - G_;
      float* ob = out + (((size_t)b * P_ + (p - 1)) * 5) * T_ + t0;
      for (int task = i; task < 80; task += 64) {
        int k = task >> 4, n = task & 15;
        ob[k * T_ + n] = prob_s[k * 16 + n];
      }
    }
    __syncthreads();
    // ---- phase 4: layer-2 state update ----
    if (j < G_) {
#pragma unroll
      for (int r = 0; r < 4; ++r) {
        int task = r * G_ + j, u = task >> 4, n = task & 15;
        float ig = gs[n * 196 + u],          fg = gs[n * 196 + U_ + u];
        float gg = gs[n * 196 + 2 * U_ + u], og = gs[n * 196 + 3 * U_ + u];
        float cc = sigf(fg) * c2[r] + sigf(ig) * tanh_f(gg);
        c2[r] = cc;
        h12T[(U_ + u) * 16 + n] = sigf(og) * tanh_f(cc);
      }
    }
    __syncthreads();
  }
  // ---- epilogue: emit step p=87 ----
  if (tid < 80) {
    int k = tid >> 4, n = tid & 15;
    float a = fcbs[k];
    for (int u = 0; u < U_; ++u) a += fcws[k * U_ + u] * h12T[(U_ + u) * 16 + n];
    logit_s[k * 16 + n] = a;
  }
  __syncthreads();
  if (tid < 16) {
    int n = tid;
    float l0 = logit_s[0 * 16 + n], l1 = logit_s[1 * 16 + n], l2 = logit_s[2 * 16 + n],
          l3 = logit_s[3 * 16 + n], l4 = logit_s[4 * 16 + n];
    float m = fmaxf(fmaxf(fmaxf(l0, l1), fmaxf(l2, l3)), l4);
    float e0 = __expf(l0 - m), e1 = __expf(l1 - m), e2 = __expf(l2 - m),
          e3 = __expf(l3 - m), e4 = __expf(l4 - m);
    float rs = __builtin_amdgcn_rcpf(e0 + e1 + e2 + e3 + e4);
    prob_s[0 * 16 + n] = e0 * rs; prob_s[1 * 16 + n] = e1 * rs;
    prob_s[2 * 16 + n] = e2 * rs; prob_s[3 * 16 + n] = e3 * rs;
    prob_s[4 * 16 + n] = e4 * rs;
  }
  __syncthreads();
  if (tid < 80) {
    int k = tid >> 4, n = tid & 15;
    out[(((size_t)b * P_ + (P_ - 1)) * 5 + k) * T_ + t0 + n] = prob_s[k * 16 + n];
  }
}

extern "C" void kernel_launch(void* const* d_in, const int* in_sizes, int n_in,
                              void* d_out, int out_size, void* d_ws, size_t ws_size,
                              hipStream_t stream) {
  const float* pf   = (const float*)d_in[0];
  const float* pc   = (const float*)d_in[1];
  const float* fc1w = (const float*)d_in[2];
  const float* fc1b = (const float*)d_in[3];
  const float* fc2w = (const float*)d_in[4];
  const float* fc2b = (const float*)d_in[5];
  const float* fc3w = (const float*)d_in[6];
  const float* fc3b = (const float*)d_in[7];
  const float* wih1 = (const float*)d_in[8];
  const float* whh1 = (const float*)d_in[9];
  const float* bih1 = (const float*)d_in[10];
  const float* bhh1 = (const float*)d_in[11];
  const float* wih2 = (const float*)d_in[12];
  const float* whh2 = (const float*)d_in[13];
  const float* bih2 = (const float*)d_in[14];
  const float* bhh2 = (const float*)d_in[15];
  const float* fcw  = (const float*)d_in[16];
  const float* fcb  = (const float*)d_in[17];
  float* out = (float*)d_out;

  float* ctxg = (float*)d_ws;
  const size_t CTXG_BYTES = (size_t)B_ * P_ * G_ * sizeof(float);  // 1,081,344
  char* xgp = (char*)d_ws + CTXG_BYTES;
  const size_t XG_ELEMS = (size_t)P_ * N_ * G_;  // 69,271,552
  const size_t SMEM = 131680;  // dynamic LDS bytes for scan_kernel (<160 KiB)

  ctx_kernel<<<22, 64, 0, stream>>>(pc, fc1w, fc1b, fc2w, fc2b, fc3w, fc3b,
                                    wih1, bih1, bhh1, ctxg);
  if (ws_size >= CTXG_BYTES + XG_ELEMS * sizeof(float)) {
    // fp32 xg path (preferred; needs ~278 MB workspace)
    float* xg = (float*)xgp;
    gemm_kernel<float><<<dim3(2, B_, P_), 256, 0, stream>>>(pf, wih1, ctxg, xg);
    scan_kernel<float><<<256, 256, SMEM, stream>>>(xg, whh1, wih2, whh2,
                                                   bih2, bhh2, fcw, fcb, out);
  } else {
    // bf16 xg fallback (~140 MB workspace)
    __hip_bfloat16* xg = (__hip_bfloat16*)xgp;
    gemm_kernel<__hip_bfloat16><<<dim3(2, B_, P_), 256, 0, stream>>>(pf, wih1, ctxg, xg);
    scan_kernel<__hip_bfloat16><<<256, 256, SMEM, stream>>>(xg, whh1, wih2, whh2,
                                                            bih2, bhh2, fcw, fcb, out);
  }
}

// Round 2
// 1627.151 us; speedup vs baseline: 1.3339x; 1.3339x over previous
//
#include <hip/hip_runtime.h>
#include <hip/hip_bf16.h>
#include <cstdint>

#define P_ 88   // pitches (sequence length of the scan)
#define B_ 16   // batch
#define T_ 256  // timesteps (folded into batch N)
#define H_ 188  // per-pitch features
#define G_ 192  // 4*48 gates; also LSTM1 input size (188 feat + 4 ctx)
#define U_ 48   // LSTM units
#define N_ 4096 // B_*T_
#define NB 8    // batch rows per scan block

__device__ __forceinline__ float sigf(float x) {
  return __builtin_amdgcn_rcpf(1.0f + __expf(-x));
}
__device__ __forceinline__ float tanh_f(float x) {
  // tanh(x) = 1 - 2/(e^{2x}+1)
  return 1.0f - 2.0f * __builtin_amdgcn_rcpf(1.0f + __expf(2.0f * x));
}

__device__ __forceinline__ float toF(float x) { return x; }
__device__ __forceinline__ float toF(__hip_bfloat16 x) { return __bfloat162float(x); }
__device__ __forceinline__ void stF(float* p, float v) { *p = v; }
__device__ __forceinline__ void stF(__hip_bfloat16* p, float v) { *p = __float2bfloat16(v); }

// ---------------------------------------------------------------------------
// Kernel 1: context MLP -> per-(b,p) gate bias vector
// ctxg[bp][g] = bih1[g] + bhh1[g] + sum_j ce[j] * wih1[g][188+j]
// ---------------------------------------------------------------------------
__global__ void ctx_kernel(const float* __restrict__ pc,
                           const float* __restrict__ fc1w, const float* __restrict__ fc1b,
                           const float* __restrict__ fc2w, const float* __restrict__ fc2b,
                           const float* __restrict__ fc3w, const float* __restrict__ fc3b,
                           const float* __restrict__ wih1,
                           const float* __restrict__ bih1, const float* __restrict__ bhh1,
                           float* __restrict__ ctxg) {
  int bp = blockIdx.x * 64 + threadIdx.x;
  if (bp >= B_ * P_) return;
  float p0 = pc[bp * 3 + 0], p1 = pc[bp * 3 + 1], p2 = pc[bp * 3 + 2];
  float x1[16], x2[16];
#pragma unroll
  for (int jj = 0; jj < 16; ++jj)
    x1[jj] = fmaxf(0.f, fc1w[jj * 3 + 0] * p0 + fc1w[jj * 3 + 1] * p1 + fc1w[jj * 3 + 2] * p2 + fc1b[jj]);
#pragma unroll
  for (int jj = 0; jj < 16; ++jj) {
    float s = fc2b[jj];
#pragma unroll
    for (int i = 0; i < 16; ++i) s += fc2w[jj * 16 + i] * x1[i];
    x2[jj] = fmaxf(0.f, s);
  }
  float ce[4];
#pragma unroll
  for (int jj = 0; jj < 4; ++jj) {
    float s = fc3b[jj];
#pragma unroll
    for (int i = 0; i < 16; ++i) s += fc3w[jj * 16 + i] * x2[i];
    ce[jj] = s;
  }
  float* op = ctxg + (size_t)bp * G_;
  for (int g = 0; g < G_; ++g) {
    const float* wr = wih1 + (size_t)g * G_ + H_;
    op[g] = bih1[g] + bhh1[g] + ce[0] * wr[0] + ce[1] * wr[1] + ce[2] * wr[2] + ce[3] * wr[3];
  }
}

// ---------------------------------------------------------------------------
// Kernel 2: xg[p][n][g] = sum_h pf[b,p,h,t] * wih1[g][h] + ctxg[bp][g]
// Block: (tB, b, p) computes a 128t x 192g tile, K=188 chunked by 16.
// Thread tile 8t x 12g (96 accs). fp32 VALU GEMM (no fp32 MFMA on CDNA4).
// ---------------------------------------------------------------------------
template <typename XT>
__global__ __launch_bounds__(256) void gemm_kernel(const float* __restrict__ pf,
                                                   const float* __restrict__ wih1,
                                                   const float* __restrict__ ctxg,
                                                   XT* __restrict__ xg) {
  const int tB = blockIdx.x, b = blockIdx.y, p = blockIdx.z;
  const int tid = threadIdx.x;
  __shared__ __align__(16) float Als[16][128];  // A chunk: [hh][t]
  __shared__ __align__(16) float Wls[16][196];  // W chunk transposed: [hh][g], padded row
  const int gtile = tid & 15, ttile = tid >> 4;
  const int t0 = ttile * 8, g0 = gtile * 12;
  float acc[8][12];
#pragma unroll
  for (int i = 0; i < 8; ++i)
#pragma unroll
    for (int j2 = 0; j2 < 12; ++j2) acc[i][j2] = 0.f;
  const float* Ab = pf + ((size_t)(b * P_ + p) * H_) * T_ + tB * 128;
  for (int kc = 0; kc < 12; ++kc) {
    const int h0 = kc * 16;
    const int kk = (kc < 11) ? 16 : 12;  // 188 = 11*16 + 12
    __syncthreads();
#pragma unroll
    for (int r = 0; r < 8; ++r) {
      int idx = r * 256 + tid, hh = idx >> 7, t = idx & 127;
      if (hh < kk) Als[hh][t] = Ab[(size_t)(h0 + hh) * T_ + t];
    }
#pragma unroll
    for (int r = 0; r < 12; ++r) {
      int idx = r * 256 + tid, hh = idx & 15, g = idx >> 4;
      if (hh < kk) Wls[hh][g] = wih1[(size_t)g * G_ + h0 + hh];
    }
    __syncthreads();
    for (int hh = 0; hh < kk; ++hh) {
      float a[8], w[12];
      *(float4*)&a[0] = *(const float4*)&Als[hh][t0];
      *(float4*)&a[4] = *(const float4*)&Als[hh][t0 + 4];
      *(float4*)&w[0] = *(const float4*)&Wls[hh][g0];
      *(float4*)&w[4] = *(const float4*)&Wls[hh][g0 + 4];
      *(float4*)&w[8] = *(const float4*)&Wls[hh][g0 + 8];
#pragma unroll
      for (int i = 0; i < 8; ++i)
#pragma unroll
        for (int j2 = 0; j2 < 12; ++j2) acc[i][j2] += a[i] * w[j2];
    }
  }
  float cg[12];
  const float* cb = ctxg + ((size_t)b * P_ + p) * G_ + g0;
#pragma unroll
  for (int j2 = 0; j2 < 12; ++j2) cg[j2] = cb[j2];
  XT* ob = xg + ((size_t)p * N_ + (size_t)b * T_ + tB * 128 + t0) * G_ + g0;
#pragma unroll
  for (int i = 0; i < 8; ++i)
#pragma unroll
    for (int j2 = 0; j2 < 12; ++j2) stF(ob + (size_t)i * G_ + j2, acc[i][j2] + cg[j2]);
}

// ---------------------------------------------------------------------------
// Kernel 3: persistent 2-layer LSTM scan over p=0..87 + fc_states + softmax.
// 512 blocks x 256 threads; block owns NB=8 batch rows. Weights live in
// REGISTERS: thread j<192 holds whh1 col j (48 regs) + [wih2;whh2] col j
// (96 regs). LDS only holds h-state + gate staging (~11 KB) -> 2 blocks/CU,
// 2 waves/SIMD. Wave 3 (tid>=192) overlaps prev-step logits/softmax/store.
// ---------------------------------------------------------------------------
__global__ __launch_bounds__(256, 2) void scan_kernel(
    const __hip_bfloat16* __restrict__ xg,
    const float* __restrict__ whh1, const float* __restrict__ wih2,
    const float* __restrict__ whh2, const float* __restrict__ bih2,
    const float* __restrict__ bhh2, const float* __restrict__ fcw,
    const float* __restrict__ fcb, float* __restrict__ out) {
  __shared__ __align__(16) float h12T[2 * U_][NB];   // [96][8]: h1 rows 0..47, h2 rows 48..95
  __shared__ __align__(16) float gs[NB][G_ + 4];     // [8][196] gate staging (pad 4)
  __shared__ float fcws[5 * U_];                     // fc_states weights
  __shared__ float logit_s[5][NB];
  __shared__ float prob_s[5][NB];

  const int tid = threadIdx.x;
  const int j = tid;                   // gate id for tid<192
  const int n0 = blockIdx.x * NB;
  const int b = n0 >> 8;
  const int t0 = n0 & 255;

  float w1[U_];        // whh1 column j (only defined for j<192)
  float w2[2 * U_];    // [wih2; whh2] column j
  float bias2 = 0.f;

  if (j < G_) {
    const float4* a1 = (const float4*)(whh1 + (size_t)j * U_);
#pragma unroll
    for (int q = 0; q < U_ / 4; ++q) *(float4*)&w1[q * 4] = a1[q];
    const float4* a2 = (const float4*)(wih2 + (size_t)j * U_);
#pragma unroll
    for (int q = 0; q < U_ / 4; ++q) *(float4*)&w2[q * 4] = a2[q];
    const float4* a3 = (const float4*)(whh2 + (size_t)j * U_);
#pragma unroll
    for (int q = 0; q < U_ / 4; ++q) *(float4*)&w2[U_ + q * 4] = a3[q];
    bias2 = bih2[j] + bhh2[j];
  }
  float fcbr = (tid >= G_ && tid < G_ + 40) ? fcb[(tid - G_) >> 3] : 0.f;

  for (int e = tid; e < 2 * U_ * NB; e += 256) ((float*)h12T)[e] = 0.f;
  for (int e = tid; e < 5 * U_; e += 256) fcws[e] = fcw[e];
  __syncthreads();

  float c1[2] = {0.f, 0.f}, c2[2] = {0.f, 0.f};
  float xpre[NB];
  if (j < G_) {
    const __hip_bfloat16* xb = xg + (size_t)n0 * G_ + j;
#pragma unroll
    for (int n = 0; n < NB; ++n) xpre[n] = __bfloat162float(xb[(size_t)n * G_]);
  }

  for (int p = 0; p < P_; ++p) {
    // ---- phase 1: layer-1 gates | prev-step fc_states logits (wave 3) ----
    if (j < G_) {
      float acc[NB];
#pragma unroll
      for (int n = 0; n < NB; ++n) acc[n] = xpre[n];
      if (p > 0) {
#pragma unroll
        for (int u = 0; u < U_; ++u) {
          float4 ha = *(const float4*)&h12T[u][0];
          float4 hb = *(const float4*)&h12T[u][4];
          acc[0] += w1[u] * ha.x; acc[1] += w1[u] * ha.y;
          acc[2] += w1[u] * ha.z; acc[3] += w1[u] * ha.w;
          acc[4] += w1[u] * hb.x; acc[5] += w1[u] * hb.y;
          acc[6] += w1[u] * hb.z; acc[7] += w1[u] * hb.w;
        }
      }
#pragma unroll
      for (int n = 0; n < NB; ++n) gs[n][j] = acc[n];
    } else if (p > 0) {
      const int i = j - G_;
      if (i < 40) {
        const int k = i >> 3, n = i & 7;
        float a = fcbr;
#pragma unroll
        for (int u = 0; u < U_; ++u) a += fcws[k * U_ + u] * h12T[U_ + u][n];
        logit_s[k][n] = a;
      }
    }
    __syncthreads();
    // ---- phase 2: layer-1 state update | prev-step softmax (wave 3) ----
    if (j < G_) {
#pragma unroll
      for (int r = 0; r < 2; ++r) {
        const int task = r * G_ + j;
        const int u = task >> 3, n = task & 7;
        float ig = gs[n][u],          fg = gs[n][U_ + u];
        float gg = gs[n][2 * U_ + u], og = gs[n][3 * U_ + u];
        float cc = sigf(fg) * c1[r] + sigf(ig) * tanh_f(gg);
        c1[r] = cc;
        h12T[u][n] = sigf(og) * tanh_f(cc);
      }
    } else if (p > 0 && j < G_ + NB) {
      const int n = j - G_;
      float l0 = logit_s[0][n], l1 = logit_s[1][n], l2 = logit_s[2][n],
            l3 = logit_s[3][n], l4 = logit_s[4][n];
      float m = fmaxf(fmaxf(fmaxf(l0, l1), fmaxf(l2, l3)), l4);
      float e0 = __expf(l0 - m), e1 = __expf(l1 - m), e2 = __expf(l2 - m),
            e3 = __expf(l3 - m), e4 = __expf(l4 - m);
      float rs = __builtin_amdgcn_rcpf(e0 + e1 + e2 + e3 + e4);
      prob_s[0][n] = e0 * rs; prob_s[1][n] = e1 * rs; prob_s[2][n] = e2 * rs;
      prob_s[3][n] = e3 * rs; prob_s[4][n] = e4 * rs;
    }
    __syncthreads();
    // ---- phase 3: layer-2 gates (+ xg prefetch) | prev-step store (wave 3) ----
    if (j < G_) {
      if (p < P_ - 1) {  // prefetch next step's xg; latency hides under K=96 loop
        const __hip_bfloat16* xb = xg + ((size_t)(p + 1) * N_ + n0) * G_ + j;
#pragma unroll
        for (int n = 0; n < NB; ++n) xpre[n] = __bfloat162float(xb[(size_t)n * G_]);
      }
      float acc[NB];
#pragma unroll
      for (int n = 0; n < NB; ++n) acc[n] = bias2;
#pragma unroll
      for (int u = 0; u < 2 * U_; ++u) {  // K=96: [h1(p); h2(p-1)]
        float4 ha = *(const float4*)&h12T[u][0];
        float4 hb = *(const float4*)&h12T[u][4];
        acc[0] += w2[u] * ha.x; acc[1] += w2[u] * ha.y;
        acc[2] += w2[u] * ha.z; acc[3] += w2[u] * ha.w;
        acc[4] += w2[u] * hb.x; acc[5] += w2[u] * hb.y;
        acc[6] += w2[u] * hb.z; acc[7] += w2[u] * hb.w;
      }
#pragma unroll
      for (int n = 0; n < NB; ++n) gs[n][j] = acc[n];
    } else if (p > 0) {
      const int i = j - G_;
      if (i < 40) {
        const int k = i >> 3, n = i & 7;
        out[(((size_t)b * P_ + (p - 1)) * 5 + k) * T_ + t0 + n] = prob_s[k][n];
      }
    }
    __syncthreads();
    // ---- phase 4: layer-2 state update ----
    if (j < G_) {
#pragma unroll
      for (int r = 0; r < 2; ++r) {
        const int task = r * G_ + j;
        const int u = task >> 3, n = task & 7;
        float ig = gs[n][u],          fg = gs[n][U_ + u];
        float gg = gs[n][2 * U_ + u], og = gs[n][3 * U_ + u];
        float cc = sigf(fg) * c2[r] + sigf(ig) * tanh_f(gg);
        c2[r] = cc;
        h12T[U_ + u][n] = sigf(og) * tanh_f(cc);
      }
    }
    __syncthreads();
  }
  // ---- epilogue: emit step p = P_-1 ----
  if (tid >= G_) {
    const int i = tid - G_;
    if (i < 40) {
      const int k = i >> 3, n = i & 7;
      float a = fcbr;
#pragma unroll
      for (int u = 0; u < U_; ++u) a += fcws[k * U_ + u] * h12T[U_ + u][n];
      logit_s[k][n] = a;
    }
  }
  __syncthreads();
  if (tid >= G_ && tid < G_ + NB) {
    const int n = tid - G_;
    float l0 = logit_s[0][n], l1 = logit_s[1][n], l2 = logit_s[2][n],
          l3 = logit_s[3][n], l4 = logit_s[4][n];
    float m = fmaxf(fmaxf(fmaxf(l0, l1), fmaxf(l2, l3)), l4);
    float e0 = __expf(l0 - m), e1 = __expf(l1 - m), e2 = __expf(l2 - m),
          e3 = __expf(l3 - m), e4 = __expf(l4 - m);
    float rs = __builtin_amdgcn_rcpf(e0 + e1 + e2 + e3 + e4);
    prob_s[0][n] = e0 * rs; prob_s[1][n] = e1 * rs; prob_s[2][n] = e2 * rs;
    prob_s[3][n] = e3 * rs; prob_s[4][n] = e4 * rs;
  }
  __syncthreads();
  if (tid >= G_) {
    const int i = tid - G_;
    if (i < 40) {
      const int k = i >> 3, n = i & 7;
      out[(((size_t)b * P_ + (P_ - 1)) * 5 + k) * T_ + t0 + n] = prob_s[k][n];
    }
  }
}

extern "C" void kernel_launch(void* const* d_in, const int* in_sizes, int n_in,
                              void* d_out, int out_size, void* d_ws, size_t ws_size,
                              hipStream_t stream) {
  const float* pf   = (const float*)d_in[0];
  const float* pc   = (const float*)d_in[1];
  const float* fc1w = (const float*)d_in[2];
  const float* fc1b = (const float*)d_in[3];
  const float* fc2w = (const float*)d_in[4];
  const float* fc2b = (const float*)d_in[5];
  const float* fc3w = (const float*)d_in[6];
  const float* fc3b = (const float*)d_in[7];
  const float* wih1 = (const float*)d_in[8];
  const float* whh1 = (const float*)d_in[9];
  const float* bih1 = (const float*)d_in[10];
  const float* bhh1 = (const float*)d_in[11];
  const float* wih2 = (const float*)d_in[12];
  const float* whh2 = (const float*)d_in[13];
  const float* bih2 = (const float*)d_in[14];
  const float* bhh2 = (const float*)d_in[15];
  const float* fcw  = (const float*)d_in[16];
  const float* fcb  = (const float*)d_in[17];
  float* out = (float*)d_out;

  float* ctxg = (float*)d_ws;
  const size_t CTXG_BYTES = (size_t)B_ * P_ * G_ * sizeof(float);  // ~1.08 MB
  __hip_bfloat16* xg = (__hip_bfloat16*)((char*)d_ws + CTXG_BYTES);  // ~138.5 MB

  ctx_kernel<<<22, 64, 0, stream>>>(pc, fc1w, fc1b, fc2w, fc2b, fc3w, fc3b,
                                    wih1, bih1, bhh1, ctxg);
  gemm_kernel<__hip_bfloat16><<<dim3(2, B_, P_), 256, 0, stream>>>(pf, wih1, ctxg, xg);
  scan_kernel<<<N_ / NB, 256, 0, stream>>>(xg, whh1, wih2, whh2,
                                           bih2, bhh2, fcw, fcb, out);
}

// Round 3
// 1592.480 us; speedup vs baseline: 1.3629x; 1.0218x over previous
//
#include <hip/hip_runtime.h>
#include <hip/hip_bf16.h>
#include <cstdint>

#define P_ 88   // pitches (sequence length of the scan)
#define B_ 16   // batch
#define T_ 256  // timesteps (folded into batch N)
#define H_ 188  // per-pitch features
#define G_ 192  // 4*48 gates; also LSTM1 input size (188 feat + 4 ctx)
#define U_ 48   // LSTM units
#define N_ 4096 // B_*T_
#define NB 8    // batch rows per scan block

__device__ __forceinline__ float sigf(float x) {
  return __builtin_amdgcn_rcpf(1.0f + __expf(-x));
}
__device__ __forceinline__ float tanh_f(float x) {
  // tanh(x) = 1 - 2/(e^{2x}+1)
  return 1.0f - 2.0f * __builtin_amdgcn_rcpf(1.0f + __expf(2.0f * x));
}

__device__ __forceinline__ float toF(float x) { return x; }
__device__ __forceinline__ float toF(__hip_bfloat16 x) { return __bfloat162float(x); }
__device__ __forceinline__ void stF(float* p, float v) { *p = v; }
__device__ __forceinline__ void stF(__hip_bfloat16* p, float v) { *p = __float2bfloat16(v); }

// ---------------------------------------------------------------------------
// Kernel 1: context MLP -> per-(b,p) gate bias vector
// ctxg[bp][g] = bih1[g] + bhh1[g] + sum_j ce[j] * wih1[g][188+j]
// ---------------------------------------------------------------------------
__global__ void ctx_kernel(const float* __restrict__ pc,
                           const float* __restrict__ fc1w, const float* __restrict__ fc1b,
                           const float* __restrict__ fc2w, const float* __restrict__ fc2b,
                           const float* __restrict__ fc3w, const float* __restrict__ fc3b,
                           const float* __restrict__ wih1,
                           const float* __restrict__ bih1, const float* __restrict__ bhh1,
                           float* __restrict__ ctxg) {
  int bp = blockIdx.x * 64 + threadIdx.x;
  if (bp >= B_ * P_) return;
  float p0 = pc[bp * 3 + 0], p1 = pc[bp * 3 + 1], p2 = pc[bp * 3 + 2];
  float x1[16], x2[16];
#pragma unroll
  for (int jj = 0; jj < 16; ++jj)
    x1[jj] = fmaxf(0.f, fc1w[jj * 3 + 0] * p0 + fc1w[jj * 3 + 1] * p1 + fc1w[jj * 3 + 2] * p2 + fc1b[jj]);
#pragma unroll
  for (int jj = 0; jj < 16; ++jj) {
    float s = fc2b[jj];
#pragma unroll
    for (int i = 0; i < 16; ++i) s += fc2w[jj * 16 + i] * x1[i];
    x2[jj] = fmaxf(0.f, s);
  }
  float ce[4];
#pragma unroll
  for (int jj = 0; jj < 4; ++jj) {
    float s = fc3b[jj];
#pragma unroll
    for (int i = 0; i < 16; ++i) s += fc3w[jj * 16 + i] * x2[i];
    ce[jj] = s;
  }
  float* op = ctxg + (size_t)bp * G_;
  for (int g = 0; g < G_; ++g) {
    const float* wr = wih1 + (size_t)g * G_ + H_;
    op[g] = bih1[g] + bhh1[g] + ce[0] * wr[0] + ce[1] * wr[1] + ce[2] * wr[2] + ce[3] * wr[3];
  }
}

// ---------------------------------------------------------------------------
// Kernel 2: xg[p][n][g] = sum_h pf[b,p,h,t] * wih1[g][h] + ctxg[bp][g]
// Block: (tB, b, p) computes a 128t x 192g tile, K=188 chunked by 16.
// Thread tile 8t x 12g (96 accs). fp32 VALU GEMM (no fp32 MFMA on CDNA4).
// ---------------------------------------------------------------------------
template <typename XT>
__global__ __launch_bounds__(256) void gemm_kernel(const float* __restrict__ pf,
                                                   const float* __restrict__ wih1,
                                                   const float* __restrict__ ctxg,
                                                   XT* __restrict__ xg) {
  const int tB = blockIdx.x, b = blockIdx.y, p = blockIdx.z;
  const int tid = threadIdx.x;
  __shared__ __align__(16) float Als[16][128];  // A chunk: [hh][t]
  __shared__ __align__(16) float Wls[16][196];  // W chunk transposed: [hh][g], padded row
  const int gtile = tid & 15, ttile = tid >> 4;
  const int t0 = ttile * 8, g0 = gtile * 12;
  float acc[8][12];
#pragma unroll
  for (int i = 0; i < 8; ++i)
#pragma unroll
    for (int j2 = 0; j2 < 12; ++j2) acc[i][j2] = 0.f;
  const float* Ab = pf + ((size_t)(b * P_ + p) * H_) * T_ + tB * 128;
  for (int kc = 0; kc < 12; ++kc) {
    const int h0 = kc * 16;
    const int kk = (kc < 11) ? 16 : 12;  // 188 = 11*16 + 12
    __syncthreads();
#pragma unroll
    for (int r = 0; r < 8; ++r) {
      int idx = r * 256 + tid, hh = idx >> 7, t = idx & 127;
      if (hh < kk) Als[hh][t] = Ab[(size_t)(h0 + hh) * T_ + t];
    }
#pragma unroll
    for (int r = 0; r < 12; ++r) {
      int idx = r * 256 + tid, hh = idx & 15, g = idx >> 4;
      if (hh < kk) Wls[hh][g] = wih1[(size_t)g * G_ + h0 + hh];
    }
    __syncthreads();
    for (int hh = 0; hh < kk; ++hh) {
      // float4 reads from LDS into named vectors, then scalar arrays filled
      // with constant indices (SROA-safe; no pointer-punned private stores).
      float4 a0 = *(const float4*)&Als[hh][t0];
      float4 a1 = *(const float4*)&Als[hh][t0 + 4];
      float4 wv0 = *(const float4*)&Wls[hh][g0];
      float4 wv1 = *(const float4*)&Wls[hh][g0 + 4];
      float4 wv2 = *(const float4*)&Wls[hh][g0 + 8];
      float av[8], wv[12];
      av[0] = a0.x; av[1] = a0.y; av[2] = a0.z; av[3] = a0.w;
      av[4] = a1.x; av[5] = a1.y; av[6] = a1.z; av[7] = a1.w;
      wv[0] = wv0.x; wv[1] = wv0.y; wv[2] = wv0.z; wv[3] = wv0.w;
      wv[4] = wv1.x; wv[5] = wv1.y; wv[6] = wv1.z; wv[7] = wv1.w;
      wv[8] = wv2.x; wv[9] = wv2.y; wv[10] = wv2.z; wv[11] = wv2.w;
#pragma unroll
      for (int i = 0; i < 8; ++i)
#pragma unroll
        for (int j2 = 0; j2 < 12; ++j2) acc[i][j2] += av[i] * wv[j2];
    }
  }
  float cg[12];
  const float* cb = ctxg + ((size_t)b * P_ + p) * G_ + g0;
#pragma unroll
  for (int j2 = 0; j2 < 12; ++j2) cg[j2] = cb[j2];
  XT* ob = xg + ((size_t)p * N_ + (size_t)b * T_ + tB * 128 + t0) * G_ + g0;
#pragma unroll
  for (int i = 0; i < 8; ++i)
#pragma unroll
    for (int j2 = 0; j2 < 12; ++j2) stF(ob + (size_t)i * G_ + j2, acc[i][j2] + cg[j2]);
}

// ---------------------------------------------------------------------------
// Kernel 3: persistent 2-layer LSTM scan over p=0..87 + fc_states + softmax.
// 512 blocks x 256 threads; block owns NB=8 batch rows. Weights live in
// REGISTERS: thread j<192 holds whh1 col j (48 regs) + [wih2;whh2] col j
// (96 regs) — loaded with scalar constant-index assignments so SROA promotes
// them (round-2 float4-punning kept them in scratch: 1 GB spill traffic).
// LDS ~11 KB. Wave 3 (tid>=192) overlaps prev-step logits/softmax/store.
// ---------------------------------------------------------------------------
__global__ __launch_bounds__(256, 2) void scan_kernel(
    const __hip_bfloat16* __restrict__ xg,
    const float* __restrict__ whh1, const float* __restrict__ wih2,
    const float* __restrict__ whh2, const float* __restrict__ bih2,
    const float* __restrict__ bhh2, const float* __restrict__ fcw,
    const float* __restrict__ fcb, float* __restrict__ out) {
  __shared__ __align__(16) float h12T[2 * U_][NB];   // [96][8]: h1 rows 0..47, h2 rows 48..95
  __shared__ __align__(16) float gs[NB][G_ + 4];     // [8][196] gate staging (pad 4)
  __shared__ float fcws[5 * U_];                     // fc_states weights
  __shared__ float logit_s[5][NB];
  __shared__ float prob_s[5][NB];

  const int tid = threadIdx.x;
  const int j = tid;                   // gate id for tid<192
  const int n0 = blockIdx.x * NB;
  const int b = n0 >> 8;
  const int t0 = n0 & 255;

  float w1[U_];        // whh1 column j (only defined for j<192)
  float w2[2 * U_];    // [wih2; whh2] column j
  float bias2 = 0.f;

  if (j < G_) {
    const float* a1 = whh1 + (size_t)j * U_;
    const float* a2 = wih2 + (size_t)j * U_;
    const float* a3 = whh2 + (size_t)j * U_;
#pragma unroll
    for (int q = 0; q < U_; ++q) w1[q] = a1[q];
#pragma unroll
    for (int q = 0; q < U_; ++q) w2[q] = a2[q];
#pragma unroll
    for (int q = 0; q < U_; ++q) w2[U_ + q] = a3[q];
    bias2 = bih2[j] + bhh2[j];
  } else {
#pragma unroll
    for (int q = 0; q < U_; ++q) w1[q] = 0.f;
#pragma unroll
    for (int q = 0; q < 2 * U_; ++q) w2[q] = 0.f;
  }
  float fcbr = (tid >= G_ && tid < G_ + 40) ? fcb[(tid - G_) >> 3] : 0.f;

  for (int e = tid; e < 2 * U_ * NB; e += 256) ((float*)h12T)[e] = 0.f;
  for (int e = tid; e < 5 * U_; e += 256) fcws[e] = fcw[e];
  __syncthreads();

  float c1[2] = {0.f, 0.f}, c2[2] = {0.f, 0.f};
  float xpre[NB];
  if (j < G_) {
    const __hip_bfloat16* xb = xg + (size_t)n0 * G_ + j;
#pragma unroll
    for (int n = 0; n < NB; ++n) xpre[n] = __bfloat162float(xb[(size_t)n * G_]);
  }

  for (int p = 0; p < P_; ++p) {
    // ---- phase 1: layer-1 gates | prev-step fc_states logits (wave 3) ----
    if (j < G_) {
      float acc[NB];
#pragma unroll
      for (int n = 0; n < NB; ++n) acc[n] = xpre[n];
      if (p > 0) {
#pragma unroll
        for (int u = 0; u < U_; ++u) {
          float4 ha = *(const float4*)&h12T[u][0];
          float4 hb = *(const float4*)&h12T[u][4];
          acc[0] += w1[u] * ha.x; acc[1] += w1[u] * ha.y;
          acc[2] += w1[u] * ha.z; acc[3] += w1[u] * ha.w;
          acc[4] += w1[u] * hb.x; acc[5] += w1[u] * hb.y;
          acc[6] += w1[u] * hb.z; acc[7] += w1[u] * hb.w;
        }
      }
#pragma unroll
      for (int n = 0; n < NB; ++n) gs[n][j] = acc[n];
    } else if (p > 0) {
      const int i = j - G_;
      if (i < 40) {
        const int k = i >> 3, n = i & 7;
        float a = fcbr;
#pragma unroll
        for (int u = 0; u < U_; ++u) a += fcws[k * U_ + u] * h12T[U_ + u][n];
        logit_s[k][n] = a;
      }
    }
    __syncthreads();
    // ---- phase 2: layer-1 state update | prev-step softmax (wave 3) ----
    if (j < G_) {
#pragma unroll
      for (int r = 0; r < 2; ++r) {
        const int task = r * G_ + j;
        const int u = task >> 3, n = task & 7;
        float ig = gs[n][u],          fg = gs[n][U_ + u];
        float gg = gs[n][2 * U_ + u], og = gs[n][3 * U_ + u];
        float cc = sigf(fg) * c1[r] + sigf(ig) * tanh_f(gg);
        c1[r] = cc;
        h12T[u][n] = sigf(og) * tanh_f(cc);
      }
    } else if (p > 0 && j < G_ + NB) {
      const int n = j - G_;
      float l0 = logit_s[0][n], l1 = logit_s[1][n], l2 = logit_s[2][n],
            l3 = logit_s[3][n], l4 = logit_s[4][n];
      float m = fmaxf(fmaxf(fmaxf(l0, l1), fmaxf(l2, l3)), l4);
      float e0 = __expf(l0 - m), e1 = __expf(l1 - m), e2 = __expf(l2 - m),
            e3 = __expf(l3 - m), e4 = __expf(l4 - m);
      float rs = __builtin_amdgcn_rcpf(e0 + e1 + e2 + e3 + e4);
      prob_s[0][n] = e0 * rs; prob_s[1][n] = e1 * rs; prob_s[2][n] = e2 * rs;
      prob_s[3][n] = e3 * rs; prob_s[4][n] = e4 * rs;
    }
    __syncthreads();
    // ---- phase 3: layer-2 gates (+ xg prefetch) | prev-step store (wave 3) ----
    if (j < G_) {
      if (p < P_ - 1) {  // prefetch next step's xg; latency hides under K=96 loop
        const __hip_bfloat16* xb = xg + ((size_t)(p + 1) * N_ + n0) * G_ + j;
#pragma unroll
        for (int n = 0; n < NB; ++n) xpre[n] = __bfloat162float(xb[(size_t)n * G_]);
      }
      float acc[NB];
#pragma unroll
      for (int n = 0; n < NB; ++n) acc[n] = bias2;
#pragma unroll
      for (int u = 0; u < 2 * U_; ++u) {  // K=96: [h1(p); h2(p-1)]
        float4 ha = *(const float4*)&h12T[u][0];
        float4 hb = *(const float4*)&h12T[u][4];
        acc[0] += w2[u] * ha.x; acc[1] += w2[u] * ha.y;
        acc[2] += w2[u] * ha.z; acc[3] += w2[u] * ha.w;
        acc[4] += w2[u] * hb.x; acc[5] += w2[u] * hb.y;
        acc[6] += w2[u] * hb.z; acc[7] += w2[u] * hb.w;
      }
#pragma unroll
      for (int n = 0; n < NB; ++n) gs[n][j] = acc[n];
    } else if (p > 0) {
      const int i = j - G_;
      if (i < 40) {
        const int k = i >> 3, n = i & 7;
        out[(((size_t)b * P_ + (p - 1)) * 5 + k) * T_ + t0 + n] = prob_s[k][n];
      }
    }
    __syncthreads();
    // ---- phase 4: layer-2 state update ----
    if (j < G_) {
#pragma unroll
      for (int r = 0; r < 2; ++r) {
        const int task = r * G_ + j;
        const int u = task >> 3, n = task & 7;
        float ig = gs[n][u],          fg = gs[n][U_ + u];
        float gg = gs[n][2 * U_ + u], og = gs[n][3 * U_ + u];
        float cc = sigf(fg) * c2[r] + sigf(ig) * tanh_f(gg);
        c2[r] = cc;
        h12T[U_ + u][n] = sigf(og) * tanh_f(cc);
      }
    }
    __syncthreads();
  }
  // ---- epilogue: emit step p = P_-1 ----
  if (tid >= G_) {
    const int i = tid - G_;
    if (i < 40) {
      const int k = i >> 3, n = i & 7;
      float a = fcbr;
#pragma unroll
      for (int u = 0; u < U_; ++u) a += fcws[k * U_ + u] * h12T[U_ + u][n];
      logit_s[k][n] = a;
    }
  }
  __syncthreads();
  if (tid >= G_ && tid < G_ + NB) {
    const int n = tid - G_;
    float l0 = logit_s[0][n], l1 = logit_s[1][n], l2 = logit_s[2][n],
          l3 = logit_s[3][n], l4 = logit_s[4][n];
    float m = fmaxf(fmaxf(fmaxf(l0, l1), fmaxf(l2, l3)), l4);
    float e0 = __expf(l0 - m), e1 = __expf(l1 - m), e2 = __expf(l2 - m),
          e3 = __expf(l3 - m), e4 = __expf(l4 - m);
    float rs = __builtin_amdgcn_rcpf(e0 + e1 + e2 + e3 + e4);
    prob_s[0][n] = e0 * rs; prob_s[1][n] = e1 * rs; prob_s[2][n] = e2 * rs;
    prob_s[3][n] = e3 * rs; prob_s[4][n] = e4 * rs;
  }
  __syncthreads();
  if (tid >= G_) {
    const int i = tid - G_;
    if (i < 40) {
      const int k = i >> 3, n = i & 7;
      out[(((size_t)b * P_ + (P_ - 1)) * 5 + k) * T_ + t0 + n] = prob_s[k][n];
    }
  }
}

extern "C" void kernel_launch(void* const* d_in, const int* in_sizes, int n_in,
                              void* d_out, int out_size, void* d_ws, size_t ws_size,
                              hipStream_t stream) {
  const float* pf   = (const float*)d_in[0];
  const float* pc   = (const float*)d_in[1];
  const float* fc1w = (const float*)d_in[2];
  const float* fc1b = (const float*)d_in[3];
  const float* fc2w = (const float*)d_in[4];
  const float* fc2b = (const float*)d_in[5];
  const float* fc3w = (const float*)d_in[6];
  const float* fc3b = (const float*)d_in[7];
  const float* wih1 = (const float*)d_in[8];
  const float* whh1 = (const float*)d_in[9];
  const float* bih1 = (const float*)d_in[10];
  const float* bhh1 = (const float*)d_in[11];
  const float* wih2 = (const float*)d_in[12];
  const float* whh2 = (const float*)d_in[13];
  const float* bih2 = (const float*)d_in[14];
  const float* bhh2 = (const float*)d_in[15];
  const float* fcw  = (const float*)d_in[16];
  const float* fcb  = (const float*)d_in[17];
  float* out = (float*)d_out;

  float* ctxg = (float*)d_ws;
  const size_t CTXG_BYTES = (size_t)B_ * P_ * G_ * sizeof(float);  // ~1.08 MB
  __hip_bfloat16* xg = (__hip_bfloat16*)((char*)d_ws + CTXG_BYTES);  // ~138.5 MB

  ctx_kernel<<<22, 64, 0, stream>>>(pc, fc1w, fc1b, fc2w, fc2b, fc3w, fc3b,
                                    wih1, bih1, bhh1, ctxg);
  gemm_kernel<__hip_bfloat16><<<dim3(2, B_, P_), 256, 0, stream>>>(pf, wih1, ctxg, xg);
  scan_kernel<<<N_ / NB, 256, 0, stream>>>(xg, whh1, wih2, whh2,
                                           bih2, bhh2, fcw, fcb, out);
}

// Round 5
// 921.928 us; speedup vs baseline: 2.3543x; 1.7273x over previous
//
#include <hip/hip_runtime.h>
#include <hip/hip_bf16.h>
#include <cstdint>

#define P_ 88   // pitches (sequence length of the scan)
#define B_ 16   // batch
#define T_ 256  // timesteps (folded into batch N)
#define H_ 188  // per-pitch features
#define G_ 192  // 4*48 gates; also LSTM1 input size (188 feat + 4 ctx)
#define U_ 48   // LSTM units
#define N_ 4096 // B_*T_

typedef __attribute__((ext_vector_type(8))) short bf16x8;
typedef __attribute__((ext_vector_type(4))) float f32x4;

__device__ __forceinline__ float sigf(float x) {
  return __builtin_amdgcn_rcpf(1.0f + __expf(-x));
}
__device__ __forceinline__ float tanh_f(float x) {
  return 1.0f - 2.0f * __builtin_amdgcn_rcpf(1.0f + __expf(2.0f * x));
}
__device__ __forceinline__ unsigned short f2bs(float v) {
  union { __hip_bfloat16 h; unsigned short s; } u;
  u.h = __float2bfloat16(v);
  return u.s;
}
__device__ __forceinline__ float bs2f(unsigned short s) {
  union { unsigned int u; float f; } x;
  x.u = ((unsigned int)s) << 16;
  return x.f;
}

// ---------------------------------------------------------------------------
// Kernel 1: context MLP -> per-(b,p) gate bias vector
// ---------------------------------------------------------------------------
__global__ void ctx_kernel(const float* __restrict__ pc,
                           const float* __restrict__ fc1w, const float* __restrict__ fc1b,
                           const float* __restrict__ fc2w, const float* __restrict__ fc2b,
                           const float* __restrict__ fc3w, const float* __restrict__ fc3b,
                           const float* __restrict__ wih1,
                           const float* __restrict__ bih1, const float* __restrict__ bhh1,
                           float* __restrict__ ctxg) {
  int bp = blockIdx.x * 64 + threadIdx.x;
  if (bp >= B_ * P_) return;
  float p0 = pc[bp * 3 + 0], p1 = pc[bp * 3 + 1], p2 = pc[bp * 3 + 2];
  float x1[16], x2[16];
#pragma unroll
  for (int jj = 0; jj < 16; ++jj)
    x1[jj] = fmaxf(0.f, fc1w[jj * 3 + 0] * p0 + fc1w[jj * 3 + 1] * p1 + fc1w[jj * 3 + 2] * p2 + fc1b[jj]);
#pragma unroll
  for (int jj = 0; jj < 16; ++jj) {
    float s = fc2b[jj];
#pragma unroll
    for (int i = 0; i < 16; ++i) s += fc2w[jj * 16 + i] * x1[i];
    x2[jj] = fmaxf(0.f, s);
  }
  float ce[4];
#pragma unroll
  for (int jj = 0; jj < 4; ++jj) {
    float s = fc3b[jj];
#pragma unroll
    for (int i = 0; i < 16; ++i) s += fc3w[jj * 16 + i] * x2[i];
    ce[jj] = s;
  }
  float* op = ctxg + (size_t)bp * G_;
  for (int g = 0; g < G_; ++g) {
    const float* wr = wih1 + (size_t)g * G_ + H_;
    op[g] = bih1[g] + bhh1[g] + ce[0] * wr[0] + ce[1] * wr[1] + ce[2] * wr[2] + ce[3] * wr[3];
  }
}

// ---------------------------------------------------------------------------
// Kernel 2: xg = pf·wih1^T + ctxg, stored bf16 PERMUTED into MFMA C-fragment
// order: xg2[(p*256+nb)*3072 + ((tile*4+r)*4+q)*16 + j16]
// where n_global = nb*16 + (q*4+r), g = tile*16 + j16.
// (scan lane l = q*16+j16 then loads contiguous 64-lane runs per (tile,r))
// ---------------------------------------------------------------------------
__global__ __launch_bounds__(256) void gemm_kernel(const float* __restrict__ pf,
                                                   const float* __restrict__ wih1,
                                                   const float* __restrict__ ctxg,
                                                   unsigned short* __restrict__ xg2) {
  const int tB = blockIdx.x, b = blockIdx.y, p = blockIdx.z;
  const int tid = threadIdx.x;
  __shared__ __align__(16) float Als[16][128];  // A chunk: [hh][t]
  __shared__ __align__(16) float Wls[16][196];  // W chunk transposed: [hh][g]
  const int gtile = tid & 15, ttile = tid >> 4;
  const int t0 = ttile * 8, g0 = gtile * 12;
  float acc[8][12];
#pragma unroll
  for (int i = 0; i < 8; ++i)
#pragma unroll
    for (int j2 = 0; j2 < 12; ++j2) acc[i][j2] = 0.f;
  const float* Ab = pf + ((size_t)(b * P_ + p) * H_) * T_ + tB * 128;
  for (int kc = 0; kc < 12; ++kc) {
    const int h0 = kc * 16;
    const int kk = (kc < 11) ? 16 : 12;  // 188 = 11*16 + 12
    __syncthreads();
#pragma unroll
    for (int r = 0; r < 8; ++r) {
      int idx = r * 256 + tid, hh = idx >> 7, t = idx & 127;
      if (hh < kk) Als[hh][t] = Ab[(size_t)(h0 + hh) * T_ + t];
    }
#pragma unroll
    for (int r = 0; r < 12; ++r) {
      int idx = r * 256 + tid, hh = idx & 15, g = idx >> 4;
      if (hh < kk) Wls[hh][g] = wih1[(size_t)g * G_ + h0 + hh];
    }
    __syncthreads();
    for (int hh = 0; hh < kk; ++hh) {
      float4 a0 = *(const float4*)&Als[hh][t0];
      float4 a1 = *(const float4*)&Als[hh][t0 + 4];
      float4 wv0 = *(const float4*)&Wls[hh][g0];
      float4 wv1 = *(const float4*)&Wls[hh][g0 + 4];
      float4 wv2 = *(const float4*)&Wls[hh][g0 + 8];
      float av[8], wv[12];
      av[0] = a0.x; av[1] = a0.y; av[2] = a0.z; av[3] = a0.w;
      av[4] = a1.x; av[5] = a1.y; av[6] = a1.z; av[7] = a1.w;
      wv[0] = wv0.x; wv[1] = wv0.y; wv[2] = wv0.z; wv[3] = wv0.w;
      wv[4] = wv1.x; wv[5] = wv1.y; wv[6] = wv1.z; wv[7] = wv1.w;
      wv[8] = wv2.x; wv[9] = wv2.y; wv[10] = wv2.z; wv[11] = wv2.w;
#pragma unroll
      for (int i = 0; i < 8; ++i)
#pragma unroll
        for (int j2 = 0; j2 < 12; ++j2) acc[i][j2] += av[i] * wv[j2];
    }
  }
  float cg[12];
  const float* cb = ctxg + ((size_t)b * P_ + p) * G_ + g0;
#pragma unroll
  for (int j2 = 0; j2 < 12; ++j2) cg[j2] = cb[j2];
  const int t_base = tB * 128 + t0;
#pragma unroll
  for (int i = 0; i < 8; ++i) {
    const int ng = b * 256 + t_base + i;
    const int nb = ng >> 4, nin = ng & 15, q = nin >> 2, r = nin & 3;
    const size_t rowbase = ((size_t)p * 256 + nb) * 3072 + (size_t)(r * 4 + q) * 16;
#pragma unroll
    for (int j2 = 0; j2 < 12; ++j2) {
      const int g = g0 + j2, tile = g >> 4, j16 = g & 15;
      xg2[rowbase + tile * 256 + j16] = f2bs(acc[i][j2] + cg[j2]);
    }
  }
}

// ---------------------------------------------------------------------------
// Kernel 3: MFMA persistent scan. 256 blocks x 256 threads (4 waves), NB=16.
// Per wave: 3 N-tiles of 16 gates for each layer; weights as persistent
// B-fragments (bf16). h-state hi/lo bf16 in LDS, read as A-fragments.
// Layer1: G1 = xg + Whh1·h1 (K=48 pad 64, 2 chunks, hi+lo terms = 12 MFMA).
// Layer2: G2 = b2 + Wcat·[h1;h2] (K=96, 3 chunks, hi+lo = 18 MFMA).
// 4 barriers/step; fc_states/softmax/out overlapped on spare thread groups.
// ---------------------------------------------------------------------------
__global__ __launch_bounds__(256, 1) void scan_mfma(
    const unsigned short* __restrict__ xg2,
    const float* __restrict__ whh1, const float* __restrict__ wih2,
    const float* __restrict__ whh2, const float* __restrict__ bih2,
    const float* __restrict__ bhh2, const float* __restrict__ fcw,
    const float* __restrict__ fcb, float* __restrict__ out) {
  __shared__ __align__(16) short hh[16][104];   // h hi bits: cols 0-47 h1, 48-95 h2
  __shared__ __align__(16) short hl[16][104];   // h lo bits
  __shared__ __align__(16) float gs[16][196];   // gate staging (one layer at a time)
  __shared__ __align__(16) float h2f[16][52];   // h2 fp32 for fc_states
  __shared__ __align__(16) float fcws[5 * 48];
  __shared__ float logit_s[5][16];
  __shared__ float prob_s[5][16];

  const int tid = threadIdx.x;
  const int w = tid >> 6;   // wave 0..3
  const int l = tid & 63;
  const int lj = l & 15;    // A-row m / C col n within a 16-tile
  const int lq = l >> 4;    // quad
  const int n0 = blockIdx.x * 16;
  const int b = n0 >> 8, t0 = n0 & 255;

  // ---- persistent weight B-fragments (one-time gather) ----
  // B[k][n]: lane l holds k = kc*32 + lq*8 + e, n = tile*16 + lj.
  bf16x8 b1[3][2];
  bf16x8 b2f[3][3];
  float bias2r[3];
#pragma unroll
  for (int i = 0; i < 3; ++i) {
    const int j = w * 48 + i * 16 + lj;
    bias2r[i] = bih2[j] + bhh2[j];
#pragma unroll
    for (int kc = 0; kc < 2; ++kc)
#pragma unroll
      for (int e = 0; e < 8; ++e) {
        const int u = kc * 32 + lq * 8 + e;
        b1[i][kc][e] = (u < U_) ? (short)f2bs(whh1[j * U_ + u]) : (short)0;
      }
#pragma unroll
    for (int kc = 0; kc < 3; ++kc)
#pragma unroll
      for (int e = 0; e < 8; ++e) {
        const int u = kc * 32 + lq * 8 + e;
        b2f[i][kc][e] = (u < U_) ? (short)f2bs(wih2[j * U_ + u])
                                 : (short)f2bs(whh2[j * U_ + (u - U_)]);
      }
  }

  for (int e = tid; e < 16 * 104 / 2; e += 256) {
    ((unsigned int*)hh)[e] = 0u;
    ((unsigned int*)hl)[e] = 0u;
  }
  for (int e = tid; e < 5 * U_; e += 256) fcws[e] = fcw[e];

  // activation task assignment: 768 (n,u) tasks, 3 per thread
  int tn[3], tu[3];
  float c1r[3] = {0.f, 0.f, 0.f}, c2r[3] = {0.f, 0.f, 0.f};
#pragma unroll
  for (int s = 0; s < 3; ++s) {
    const int task = tid + 256 * s;
    tn[s] = task / U_;
    tu[s] = task % U_;
  }
  // fc-logit threads (0..79), softmax threads (192..207), store threads (96..175)
  const bool fcth = tid < 80;
  const int fk = tid >> 4, fn = tid & 15;
  const float fcbr = fcth ? fcb[fk] : 0.f;
  const int sk = (tid - 96) >> 4, sn = (tid - 96) & 15;

  // xg prefetch for p=0
  unsigned short xp[12];
  {
    const size_t pb = (size_t)blockIdx.x * 3072;
#pragma unroll
    for (int i = 0; i < 3; ++i)
#pragma unroll
      for (int r = 0; r < 4; ++r)
        xp[i * 4 + r] = xg2[pb + (size_t)((w * 3 + i) * 256 + r * 64 + l)];
  }
  const short* hhrow = &hh[lj][0];
  const short* hlrow = &hl[lj][0];
  __syncthreads();

  for (int p = 0; p < P_; ++p) {
    // ---- PHASE A: L1 MFMA (C init = xg) | fc_states logits for p-1 ----
    f32x4 c1f[3];
#pragma unroll
    for (int i = 0; i < 3; ++i)
#pragma unroll
      for (int r = 0; r < 4; ++r) c1f[i][r] = bs2f(xp[i * 4 + r]);
    {
      bf16x8 ah0 = *(const bf16x8*)(hhrow + lq * 8);
      bf16x8 ah1 = *(const bf16x8*)(hhrow + 32 + lq * 8);
      bf16x8 al0 = *(const bf16x8*)(hlrow + lq * 8);
      bf16x8 al1 = *(const bf16x8*)(hlrow + 32 + lq * 8);
#pragma unroll
      for (int i = 0; i < 3; ++i)
        c1f[i] = __builtin_amdgcn_mfma_f32_16x16x32_bf16(ah0, b1[i][0], c1f[i], 0, 0, 0);
#pragma unroll
      for (int i = 0; i < 3; ++i)
        c1f[i] = __builtin_amdgcn_mfma_f32_16x16x32_bf16(ah1, b1[i][1], c1f[i], 0, 0, 0);
#pragma unroll
      for (int i = 0; i < 3; ++i)
        c1f[i] = __builtin_amdgcn_mfma_f32_16x16x32_bf16(al0, b1[i][0], c1f[i], 0, 0, 0);
#pragma unroll
      for (int i = 0; i < 3; ++i)
        c1f[i] = __builtin_amdgcn_mfma_f32_16x16x32_bf16(al1, b1[i][1], c1f[i], 0, 0, 0);
    }
#pragma unroll
    for (int i = 0; i < 3; ++i)
#pragma unroll
      for (int r = 0; r < 4; ++r)
        gs[lq * 4 + r][w * 48 + i * 16 + lj] = c1f[i][r];
    if (p > 0 && fcth) {
      float a = fcbr;
#pragma unroll
      for (int uq = 0; uq < 12; ++uq) {
        f32x4 hv = *(const f32x4*)&h2f[fn][uq * 4];
        f32x4 wv = *(const f32x4*)&fcws[fk * 48 + uq * 4];
        a += hv[0] * wv[0] + hv[1] * wv[1] + hv[2] * wv[2] + hv[3] * wv[3];
      }
      logit_s[fk][fn] = a;
    }
    __syncthreads();
    // ---- PHASE B: L1 activations/h1 update | softmax for p-1 ----
#pragma unroll
    for (int s = 0; s < 3; ++s) {
      const int n = tn[s], u = tu[s];
      const float ig = gs[n][u], fg = gs[n][48 + u];
      const float gg = gs[n][96 + u], og = gs[n][144 + u];
      const float cc = sigf(fg) * c1r[s] + sigf(ig) * tanh_f(gg);
      c1r[s] = cc;
      const float h = sigf(og) * tanh_f(cc);
      const unsigned short hb = f2bs(h);
      hh[n][u] = (short)hb;
      hl[n][u] = (short)f2bs(h - bs2f(hb));
    }
    if (p > 0 && tid >= 192 && tid < 208) {
      const int n = tid - 192;
      const float l0 = logit_s[0][n], l1 = logit_s[1][n], l2 = logit_s[2][n],
                  l3 = logit_s[3][n], l4 = logit_s[4][n];
      const float m = fmaxf(fmaxf(fmaxf(l0, l1), fmaxf(l2, l3)), l4);
      const float e0 = __expf(l0 - m), e1 = __expf(l1 - m), e2 = __expf(l2 - m),
                  e3 = __expf(l3 - m), e4 = __expf(l4 - m);
      const float rs = __builtin_amdgcn_rcpf(e0 + e1 + e2 + e3 + e4);
      prob_s[0][n] = e0 * rs; prob_s[1][n] = e1 * rs; prob_s[2][n] = e2 * rs;
      prob_s[3][n] = e3 * rs; prob_s[4][n] = e4 * rs;
    }
    __syncthreads();
    // ---- PHASE C: L2 MFMA (+ xg prefetch p+1) | store p-1 ----
    if (p < P_ - 1) {
      const size_t pb = (size_t)((p + 1) * 256 + blockIdx.x) * 3072;
#pragma unroll
      for (int i = 0; i < 3; ++i)
#pragma unroll
        for (int r = 0; r < 4; ++r)
          xp[i * 4 + r] = xg2[pb + (size_t)((w * 3 + i) * 256 + r * 64 + l)];
    }
    f32x4 c2f[3];
#pragma unroll
    for (int i = 0; i < 3; ++i) {
      c2f[i][0] = bias2r[i]; c2f[i][1] = bias2r[i];
      c2f[i][2] = bias2r[i]; c2f[i][3] = bias2r[i];
    }
    {
      bf16x8 a0 = *(const bf16x8*)(hhrow + lq * 8);
      bf16x8 a1 = *(const bf16x8*)(hhrow + 32 + lq * 8);
      bf16x8 a2 = *(const bf16x8*)(hhrow + 64 + lq * 8);
      bf16x8 q0 = *(const bf16x8*)(hlrow + lq * 8);
      bf16x8 q1 = *(const bf16x8*)(hlrow + 32 + lq * 8);
      bf16x8 q2 = *(const bf16x8*)(hlrow + 64 + lq * 8);
#pragma unroll
      for (int i = 0; i < 3; ++i)
        c2f[i] = __builtin_amdgcn_mfma_f32_16x16x32_bf16(a0, b2f[i][0], c2f[i], 0, 0, 0);
#pragma unroll
      for (int i = 0; i < 3; ++i)
        c2f[i] = __builtin_amdgcn_mfma_f32_16x16x32_bf16(a1, b2f[i][1], c2f[i], 0, 0, 0);
#pragma unroll
      for (int i = 0; i < 3; ++i)
        c2f[i] = __builtin_amdgcn_mfma_f32_16x16x32_bf16(a2, b2f[i][2], c2f[i], 0, 0, 0);
#pragma unroll
      for (int i = 0; i < 3; ++i)
        c2f[i] = __builtin_amdgcn_mfma_f32_16x16x32_bf16(q0, b2f[i][0], c2f[i], 0, 0, 0);
#pragma unroll
      for (int i = 0; i < 3; ++i)
        c2f[i] = __builtin_amdgcn_mfma_f32_16x16x32_bf16(q1, b2f[i][1], c2f[i], 0, 0, 0);
#pragma unroll
      for (int i = 0; i < 3; ++i)
        c2f[i] = __builtin_amdgcn_mfma_f32_16x16x32_bf16(q2, b2f[i][2], c2f[i], 0, 0, 0);
    }
#pragma unroll
    for (int i = 0; i < 3; ++i)
#pragma unroll
      for (int r = 0; r < 4; ++r)
        gs[lq * 4 + r][w * 48 + i * 16 + lj] = c2f[i][r];
    if (p > 0 && tid >= 96 && tid < 176) {
      out[(((size_t)b * P_ + (p - 1)) * 5 + sk) * T_ + t0 + sn] = prob_s[sk][sn];
    }
    __syncthreads();
    // ---- PHASE D: L2 activations/h2 update ----
#pragma unroll
    for (int s = 0; s < 3; ++s) {
      const int n = tn[s], u = tu[s];
      const float ig = gs[n][u], fg = gs[n][48 + u];
      const float gg = gs[n][96 + u], og = gs[n][144 + u];
      const float cc = sigf(fg) * c2r[s] + sigf(ig) * tanh_f(gg);
      c2r[s] = cc;
      const float h = sigf(og) * tanh_f(cc);
      const unsigned short hb = f2bs(h);
      hh[n][48 + u] = (short)hb;
      hl[n][48 + u] = (short)f2bs(h - bs2f(hb));
      h2f[n][u] = h;
    }
    __syncthreads();
  }
  // ---- epilogue: fc/softmax/store for p = P_-1 ----
  if (fcth) {
    float a = fcbr;
#pragma unroll
    for (int uq = 0; uq < 12; ++uq) {
      f32x4 hv = *(const f32x4*)&h2f[fn][uq * 4];
      f32x4 wv = *(const f32x4*)&fcws[fk * 48 + uq * 4];
      a += hv[0] * wv[0] + hv[1] * wv[1] + hv[2] * wv[2] + hv[3] * wv[3];
    }
    logit_s[fk][fn] = a;
  }
  __syncthreads();
  if (tid >= 192 && tid < 208) {
    const int n = tid - 192;
    const float l0 = logit_s[0][n], l1 = logit_s[1][n], l2 = logit_s[2][n],
                l3 = logit_s[3][n], l4 = logit_s[4][n];
    const float m = fmaxf(fmaxf(fmaxf(l0, l1), fmaxf(l2, l3)), l4);
    const float e0 = __expf(l0 - m), e1 = __expf(l1 - m), e2 = __expf(l2 - m),
                e3 = __expf(l3 - m), e4 = __expf(l4 - m);
    const float rs = __builtin_amdgcn_rcpf(e0 + e1 + e2 + e3 + e4);
    prob_s[0][n] = e0 * rs; prob_s[1][n] = e1 * rs; prob_s[2][n] = e2 * rs;
    prob_s[3][n] = e3 * rs; prob_s[4][n] = e4 * rs;
  }
  __syncthreads();
  if (tid >= 96 && tid < 176) {
    out[(((size_t)b * P_ + (P_ - 1)) * 5 + sk) * T_ + t0 + sn] = prob_s[sk][sn];
  }
}

extern "C" void kernel_launch(void* const* d_in, const int* in_sizes, int n_in,
                              void* d_out, int out_size, void* d_ws, size_t ws_size,
                              hipStream_t stream) {
  const float* pf   = (const float*)d_in[0];
  const float* pc   = (const float*)d_in[1];
  const float* fc1w = (const float*)d_in[2];
  const float* fc1b = (const float*)d_in[3];
  const float* fc2w = (const float*)d_in[4];
  const float* fc2b = (const float*)d_in[5];
  const float* fc3w = (const float*)d_in[6];
  const float* fc3b = (const float*)d_in[7];
  const float* wih1 = (const float*)d_in[8];
  const float* whh1 = (const float*)d_in[9];
  const float* bih1 = (const float*)d_in[10];
  const float* bhh1 = (const float*)d_in[11];
  const float* wih2 = (const float*)d_in[12];
  const float* whh2 = (const float*)d_in[13];
  const float* bih2 = (const float*)d_in[14];
  const float* bhh2 = (const float*)d_in[15];
  const float* fcw  = (const float*)d_in[16];
  const float* fcb  = (const float*)d_in[17];
  float* out = (float*)d_out;

  float* ctxg = (float*)d_ws;
  const size_t CTXG_BYTES = (size_t)B_ * P_ * G_ * sizeof(float);  // ~1.08 MB
  unsigned short* xg2 = (unsigned short*)((char*)d_ws + CTXG_BYTES);  // ~138.5 MB

  ctx_kernel<<<22, 64, 0, stream>>>(pc, fc1w, fc1b, fc2w, fc2b, fc3w, fc3b,
                                    wih1, bih1, bhh1, ctxg);
  gemm_kernel<<<dim3(2, B_, P_), 256, 0, stream>>>(pf, wih1, ctxg, xg2);
  scan_mfma<<<N_ / 16, 256, 0, stream>>>(xg2, whh1, wih2, whh2,
                                         bih2, bhh2, fcw, fcb, out);
}

// Round 6
// 906.829 us; speedup vs baseline: 2.3934x; 1.0166x over previous
//
#include <hip/hip_runtime.h>
#include <hip/hip_bf16.h>
#include <cstdint>

#define P_ 88   // pitches (sequence length of the scan)
#define B_ 16   // batch
#define T_ 256  // timesteps (folded into batch N)
#define H_ 188  // per-pitch features
#define G_ 192  // 4*48 gates; also LSTM1 input size (188 feat + 4 ctx)
#define U_ 48   // LSTM units
#define N_ 4096 // B_*T_

typedef __attribute__((ext_vector_type(8))) short bf16x8;
typedef __attribute__((ext_vector_type(8))) _Float16 f16x8;
typedef __attribute__((ext_vector_type(4))) float f32x4;

__device__ __forceinline__ float sigf(float x) {
  return __builtin_amdgcn_rcpf(1.0f + __expf(-x));
}
__device__ __forceinline__ float tanh_f(float x) {
  return 1.0f - 2.0f * __builtin_amdgcn_rcpf(1.0f + __expf(2.0f * x));
}
__device__ __forceinline__ unsigned short f2bs(float v) {
  union { __hip_bfloat16 h; unsigned short s; } u;
  u.h = __float2bfloat16(v);
  return u.s;
}
__device__ __forceinline__ float bs2f(unsigned short s) {
  union { unsigned int u; float f; } x;
  x.u = ((unsigned int)s) << 16;
  return x.f;
}
__device__ __forceinline__ float hs2f(unsigned short s) {
  union { unsigned short u; _Float16 h; } x;
  x.u = s;
  return (float)x.h;
}

// ---------------------------------------------------------------------------
// Kernel 1: context MLP -> per-(b,p) gate bias vector
// ---------------------------------------------------------------------------
__global__ void ctx_kernel(const float* __restrict__ pc,
                           const float* __restrict__ fc1w, const float* __restrict__ fc1b,
                           const float* __restrict__ fc2w, const float* __restrict__ fc2b,
                           const float* __restrict__ fc3w, const float* __restrict__ fc3b,
                           const float* __restrict__ wih1,
                           const float* __restrict__ bih1, const float* __restrict__ bhh1,
                           float* __restrict__ ctxg) {
  int bp = blockIdx.x * 64 + threadIdx.x;
  if (bp >= B_ * P_) return;
  float p0 = pc[bp * 3 + 0], p1 = pc[bp * 3 + 1], p2 = pc[bp * 3 + 2];
  float x1[16], x2[16];
#pragma unroll
  for (int jj = 0; jj < 16; ++jj)
    x1[jj] = fmaxf(0.f, fc1w[jj * 3 + 0] * p0 + fc1w[jj * 3 + 1] * p1 + fc1w[jj * 3 + 2] * p2 + fc1b[jj]);
#pragma unroll
  for (int jj = 0; jj < 16; ++jj) {
    float s = fc2b[jj];
#pragma unroll
    for (int i = 0; i < 16; ++i) s += fc2w[jj * 16 + i] * x1[i];
    x2[jj] = fmaxf(0.f, s);
  }
  float ce[4];
#pragma unroll
  for (int jj = 0; jj < 4; ++jj) {
    float s = fc3b[jj];
#pragma unroll
    for (int i = 0; i < 16; ++i) s += fc3w[jj * 16 + i] * x2[i];
    ce[jj] = s;
  }
  float* op = ctxg + (size_t)bp * G_;
  for (int g = 0; g < G_; ++g) {
    const float* wr = wih1 + (size_t)g * G_ + H_;
    op[g] = bih1[g] + bhh1[g] + ce[0] * wr[0] + ce[1] * wr[1] + ce[2] * wr[2] + ce[3] * wr[3];
  }
}

// ---------------------------------------------------------------------------
// Kernel 1b: pack wih1 feature columns (k<188, pad to 192) into f16 MFMA
// B-fragment order: wfrag[(j*6+kc)*64 + l] = 8 halves, W[g=j*16+(l&15)]
// [k=kc*32+(l>>4)*8+e]. 74 KB total, L2-hot for all GEMM blocks.
// ---------------------------------------------------------------------------
__global__ __launch_bounds__(256) void wfrag_kernel(const float* __restrict__ wih1,
                                                    f16x8* __restrict__ wfrag) {
  const int idx = blockIdx.x * 256 + threadIdx.x;
  if (idx >= 12 * 6 * 64) return;
  const int l = idx & 63;
  const int kc = (idx >> 6) % 6;
  const int j = idx / 384;
  const int g = j * 16 + (l & 15);
  const int k0 = kc * 32 + (l >> 4) * 8;
  f16x8 v;
#pragma unroll
  for (int e = 0; e < 8; ++e) {
    const int k = k0 + e;
    const float wv = (k < H_) ? wih1[(size_t)g * G_ + k] : 0.f;
    v[e] = (_Float16)wv;
  }
  wfrag[idx] = v;
}

// ---------------------------------------------------------------------------
// Kernel 2: MFMA GEMM. xg = pf·wih1_feat^T + ctxg, f16 output permuted into
// the scan's C-fragment order. One block per (b,p); 4 waves; wave owns 32 t
// rows per pass (2 m-tiles), all 12 gate tiles. A = pf rows split f16 hi/lo
// (2-term MFMA, keeps fp32-level accuracy); B = prepacked f16 W fragments.
// ---------------------------------------------------------------------------
__global__ __launch_bounds__(256, 2) void gemm_mfma(const float* __restrict__ pf,
                                                    const f16x8* __restrict__ wfrag,
                                                    const float* __restrict__ ctxg,
                                                    unsigned short* __restrict__ xg2) {
  const int bp = blockIdx.x;  // b*88 + p
  const int p = bp % P_, b = bp / P_;
  const int tid = threadIdx.x;
  const int w = tid >> 6, l = tid & 63;
  const int lj = l & 15, lq = l >> 4;

  float cg[12];
#pragma unroll
  for (int jn = 0; jn < 12; ++jn)
    cg[jn] = ctxg[(size_t)bp * G_ + jn * 16 + lj];

  const float* Abase = pf + (size_t)bp * H_ * T_;

  for (int pass = 0; pass < 2; ++pass) {
    const int trow0 = pass * 128 + w * 32;
    f32x4 acc[2][12];
#pragma unroll
    for (int mt = 0; mt < 2; ++mt)
#pragma unroll
      for (int jn = 0; jn < 12; ++jn)
#pragma unroll
        for (int r = 0; r < 4; ++r) acc[mt][jn][r] = 0.f;

    for (int kc = 0; kc < 6; ++kc) {
      const int k0 = kc * 32 + lq * 8;
      f16x8 ahi[2], alo[2];
#pragma unroll
      for (int mt = 0; mt < 2; ++mt) {
        const int t = trow0 + mt * 16 + lj;
        const float* ap = Abase + t;
#pragma unroll
        for (int e = 0; e < 8; ++e) {
          const int k = k0 + e;
          const float a = (k < H_) ? ap[(size_t)k * T_] : 0.f;
          const _Float16 hi = (_Float16)a;
          ahi[mt][e] = hi;
          alo[mt][e] = (_Float16)(a - (float)hi);
        }
      }
#pragma unroll
      for (int jn = 0; jn < 12; ++jn) {
        const f16x8 wf = wfrag[(jn * 6 + kc) * 64 + l];
        acc[0][jn] = __builtin_amdgcn_mfma_f32_16x16x32_f16(ahi[0], wf, acc[0][jn], 0, 0, 0);
        acc[1][jn] = __builtin_amdgcn_mfma_f32_16x16x32_f16(ahi[1], wf, acc[1][jn], 0, 0, 0);
        acc[0][jn] = __builtin_amdgcn_mfma_f32_16x16x32_f16(alo[0], wf, acc[0][jn], 0, 0, 0);
        acc[1][jn] = __builtin_amdgcn_mfma_f32_16x16x32_f16(alo[1], wf, acc[1][jn], 0, 0, 0);
      }
    }
    // epilogue: + ctx bias, cast f16, store in scan fragment order
#pragma unroll
    for (int mt = 0; mt < 2; ++mt) {
      const int nb = b * 16 + pass * 8 + w * 2 + mt;
      unsigned short* ob = xg2 + ((size_t)p * 256 + nb) * 3072;
#pragma unroll
      for (int jn = 0; jn < 12; ++jn)
#pragma unroll
        for (int r = 0; r < 4; ++r) {
          union { _Float16 h; unsigned short s; } cv;
          cv.h = (_Float16)(acc[mt][jn][r] + cg[jn]);
          ob[jn * 256 + r * 64 + lq * 16 + lj] = cv.s;
        }
    }
  }
}

// ---------------------------------------------------------------------------
// Kernel 3: MFMA persistent scan (unchanged from round 5 except f16 xg).
// ---------------------------------------------------------------------------
__global__ __launch_bounds__(256, 1) void scan_mfma(
    const unsigned short* __restrict__ xg2,
    const float* __restrict__ whh1, const float* __restrict__ wih2,
    const float* __restrict__ whh2, const float* __restrict__ bih2,
    const float* __restrict__ bhh2, const float* __restrict__ fcw,
    const float* __restrict__ fcb, float* __restrict__ out) {
  __shared__ __align__(16) short hh[16][104];   // h hi bits: cols 0-47 h1, 48-95 h2
  __shared__ __align__(16) short hl[16][104];   // h lo bits
  __shared__ __align__(16) float gs[16][196];   // gate staging (one layer at a time)
  __shared__ __align__(16) float h2f[16][52];   // h2 fp32 for fc_states
  __shared__ __align__(16) float fcws[5 * 48];
  __shared__ float logit_s[5][16];
  __shared__ float prob_s[5][16];

  const int tid = threadIdx.x;
  const int w = tid >> 6;   // wave 0..3
  const int l = tid & 63;
  const int lj = l & 15;    // A-row m / C col n within a 16-tile
  const int lq = l >> 4;    // quad
  const int n0 = blockIdx.x * 16;
  const int b = n0 >> 8, t0 = n0 & 255;

  // ---- persistent weight B-fragments (one-time gather) ----
  bf16x8 b1[3][2];
  bf16x8 b2f[3][3];
  float bias2r[3];
#pragma unroll
  for (int i = 0; i < 3; ++i) {
    const int j = w * 48 + i * 16 + lj;
    bias2r[i] = bih2[j] + bhh2[j];
#pragma unroll
    for (int kc = 0; kc < 2; ++kc)
#pragma unroll
      for (int e = 0; e < 8; ++e) {
        const int u = kc * 32 + lq * 8 + e;
        b1[i][kc][e] = (u < U_) ? (short)f2bs(whh1[j * U_ + u]) : (short)0;
      }
#pragma unroll
    for (int kc = 0; kc < 3; ++kc)
#pragma unroll
      for (int e = 0; e < 8; ++e) {
        const int u = kc * 32 + lq * 8 + e;
        b2f[i][kc][e] = (u < U_) ? (short)f2bs(wih2[j * U_ + u])
                                 : (short)f2bs(whh2[j * U_ + (u - U_)]);
      }
  }

  for (int e = tid; e < 16 * 104 / 2; e += 256) {
    ((unsigned int*)hh)[e] = 0u;
    ((unsigned int*)hl)[e] = 0u;
  }
  for (int e = tid; e < 5 * U_; e += 256) fcws[e] = fcw[e];

  int tn[3], tu[3];
  float c1r[3] = {0.f, 0.f, 0.f}, c2r[3] = {0.f, 0.f, 0.f};
#pragma unroll
  for (int s = 0; s < 3; ++s) {
    const int task = tid + 256 * s;
    tn[s] = task / U_;
    tu[s] = task % U_;
  }
  const bool fcth = tid < 80;
  const int fk = tid >> 4, fn = tid & 15;
  const float fcbr = fcth ? fcb[fk] : 0.f;
  const int sk = (tid - 96) >> 4, sn = (tid - 96) & 15;

  unsigned short xp[12];
  {
    const size_t pb = (size_t)blockIdx.x * 3072;
#pragma unroll
    for (int i = 0; i < 3; ++i)
#pragma unroll
      for (int r = 0; r < 4; ++r)
        xp[i * 4 + r] = xg2[pb + (size_t)((w * 3 + i) * 256 + r * 64 + l)];
  }
  const short* hhrow = &hh[lj][0];
  const short* hlrow = &hl[lj][0];
  __syncthreads();

  for (int p = 0; p < P_; ++p) {
    // ---- PHASE A: L1 MFMA (C init = xg) | fc_states logits for p-1 ----
    f32x4 c1f[3];
#pragma unroll
    for (int i = 0; i < 3; ++i)
#pragma unroll
      for (int r = 0; r < 4; ++r) c1f[i][r] = hs2f(xp[i * 4 + r]);
    {
      bf16x8 ah0 = *(const bf16x8*)(hhrow + lq * 8);
      bf16x8 ah1 = *(const bf16x8*)(hhrow + 32 + lq * 8);
      bf16x8 al0 = *(const bf16x8*)(hlrow + lq * 8);
      bf16x8 al1 = *(const bf16x8*)(hlrow + 32 + lq * 8);
#pragma unroll
      for (int i = 0; i < 3; ++i)
        c1f[i] = __builtin_amdgcn_mfma_f32_16x16x32_bf16(ah0, b1[i][0], c1f[i], 0, 0, 0);
#pragma unroll
      for (int i = 0; i < 3; ++i)
        c1f[i] = __builtin_amdgcn_mfma_f32_16x16x32_bf16(ah1, b1[i][1], c1f[i], 0, 0, 0);
#pragma unroll
      for (int i = 0; i < 3; ++i)
        c1f[i] = __builtin_amdgcn_mfma_f32_16x16x32_bf16(al0, b1[i][0], c1f[i], 0, 0, 0);
#pragma unroll
      for (int i = 0; i < 3; ++i)
        c1f[i] = __builtin_amdgcn_mfma_f32_16x16x32_bf16(al1, b1[i][1], c1f[i], 0, 0, 0);
    }
#pragma unroll
    for (int i = 0; i < 3; ++i)
#pragma unroll
      for (int r = 0; r < 4; ++r)
        gs[lq * 4 + r][w * 48 + i * 16 + lj] = c1f[i][r];
    if (p > 0 && fcth) {
      float a = fcbr;
#pragma unroll
      for (int uq = 0; uq < 12; ++uq) {
        f32x4 hv = *(const f32x4*)&h2f[fn][uq * 4];
        f32x4 wv = *(const f32x4*)&fcws[fk * 48 + uq * 4];
        a += hv[0] * wv[0] + hv[1] * wv[1] + hv[2] * wv[2] + hv[3] * wv[3];
      }
      logit_s[fk][fn] = a;
    }
    __syncthreads();
    // ---- PHASE B: L1 activations/h1 update | softmax for p-1 ----
#pragma unroll
    for (int s = 0; s < 3; ++s) {
      const int n = tn[s], u = tu[s];
      const float ig = gs[n][u], fg = gs[n][48 + u];
      const float gg = gs[n][96 + u], og = gs[n][144 + u];
      const float cc = sigf(fg) * c1r[s] + sigf(ig) * tanh_f(gg);
      c1r[s] = cc;
      const float h = sigf(og) * tanh_f(cc);
      const unsigned short hb = f2bs(h);
      hh[n][u] = (short)hb;
      hl[n][u] = (short)f2bs(h - bs2f(hb));
    }
    if (p > 0 && tid >= 192 && tid < 208) {
      const int n = tid - 192;
      const float l0 = logit_s[0][n], l1 = logit_s[1][n], l2 = logit_s[2][n],
                  l3 = logit_s[3][n], l4 = logit_s[4][n];
      const float m = fmaxf(fmaxf(fmaxf(l0, l1), fmaxf(l2, l3)), l4);
      const float e0 = __expf(l0 - m), e1 = __expf(l1 - m), e2 = __expf(l2 - m),
                  e3 = __expf(l3 - m), e4 = __expf(l4 - m);
      const float rs = __builtin_amdgcn_rcpf(e0 + e1 + e2 + e3 + e4);
      prob_s[0][n] = e0 * rs; prob_s[1][n] = e1 * rs; prob_s[2][n] = e2 * rs;
      prob_s[3][n] = e3 * rs; prob_s[4][n] = e4 * rs;
    }
    __syncthreads();
    // ---- PHASE C: L2 MFMA (+ xg prefetch p+1) | store p-1 ----
    if (p < P_ - 1) {
      const size_t pb = (size_t)((p + 1) * 256 + blockIdx.x) * 3072;
#pragma unroll
      for (int i = 0; i < 3; ++i)
#pragma unroll
        for (int r = 0; r < 4; ++r)
          xp[i * 4 + r] = xg2[pb + (size_t)((w * 3 + i) * 256 + r * 64 + l)];
    }
    f32x4 c2f[3];
#pragma unroll
    for (int i = 0; i < 3; ++i) {
      c2f[i][0] = bias2r[i]; c2f[i][1] = bias2r[i];
      c2f[i][2] = bias2r[i]; c2f[i][3] = bias2r[i];
    }
    {
      bf16x8 a0 = *(const bf16x8*)(hhrow + lq * 8);
      bf16x8 a1 = *(const bf16x8*)(hhrow + 32 + lq * 8);
      bf16x8 a2 = *(const bf16x8*)(hhrow + 64 + lq * 8);
      bf16x8 q0 = *(const bf16x8*)(hlrow + lq * 8);
      bf16x8 q1 = *(const bf16x8*)(hlrow + 32 + lq * 8);
      bf16x8 q2 = *(const bf16x8*)(hlrow + 64 + lq * 8);
#pragma unroll
      for (int i = 0; i < 3; ++i)
        c2f[i] = __builtin_amdgcn_mfma_f32_16x16x32_bf16(a0, b2f[i][0], c2f[i], 0, 0, 0);
#pragma unroll
      for (int i = 0; i < 3; ++i)
        c2f[i] = __builtin_amdgcn_mfma_f32_16x16x32_bf16(a1, b2f[i][1], c2f[i], 0, 0, 0);
#pragma unroll
      for (int i = 0; i < 3; ++i)
        c2f[i] = __builtin_amdgcn_mfma_f32_16x16x32_bf16(a2, b2f[i][2], c2f[i], 0, 0, 0);
#pragma unroll
      for (int i = 0; i < 3; ++i)
        c2f[i] = __builtin_amdgcn_mfma_f32_16x16x32_bf16(q0, b2f[i][0], c2f[i], 0, 0, 0);
#pragma unroll
      for (int i = 0; i < 3; ++i)
        c2f[i] = __builtin_amdgcn_mfma_f32_16x16x32_bf16(q1, b2f[i][1], c2f[i], 0, 0, 0);
#pragma unroll
      for (int i = 0; i < 3; ++i)
        c2f[i] = __builtin_amdgcn_mfma_f32_16x16x32_bf16(q2, b2f[i][2], c2f[i], 0, 0, 0);
    }
#pragma unroll
    for (int i = 0; i < 3; ++i)
#pragma unroll
      for (int r = 0; r < 4; ++r)
        gs[lq * 4 + r][w * 48 + i * 16 + lj] = c2f[i][r];
    if (p > 0 && tid >= 96 && tid < 176) {
      out[(((size_t)b * P_ + (p - 1)) * 5 + sk) * T_ + t0 + sn] = prob_s[sk][sn];
    }
    __syncthreads();
    // ---- PHASE D: L2 activations/h2 update ----
#pragma unroll
    for (int s = 0; s < 3; ++s) {
      const int n = tn[s], u = tu[s];
      const float ig = gs[n][u], fg = gs[n][48 + u];
      const float gg = gs[n][96 + u], og = gs[n][144 + u];
      const float cc = sigf(fg) * c2r[s] + sigf(ig) * tanh_f(gg);
      c2r[s] = cc;
      const float h = sigf(og) * tanh_f(cc);
      const unsigned short hb = f2bs(h);
      hh[n][48 + u] = (short)hb;
      hl[n][48 + u] = (short)f2bs(h - bs2f(hb));
      h2f[n][u] = h;
    }
    __syncthreads();
  }
  // ---- epilogue: fc/softmax/store for p = P_-1 ----
  if (fcth) {
    float a = fcbr;
#pragma unroll
    for (int uq = 0; uq < 12; ++uq) {
      f32x4 hv = *(const f32x4*)&h2f[fn][uq * 4];
      f32x4 wv = *(const f32x4*)&fcws[fk * 48 + uq * 4];
      a += hv[0] * wv[0] + hv[1] * wv[1] + hv[2] * wv[2] + hv[3] * wv[3];
    }
    logit_s[fk][fn] = a;
  }
  __syncthreads();
  if (tid >= 192 && tid < 208) {
    const int n = tid - 192;
    const float l0 = logit_s[0][n], l1 = logit_s[1][n], l2 = logit_s[2][n],
                l3 = logit_s[3][n], l4 = logit_s[4][n];
    const float m = fmaxf(fmaxf(fmaxf(l0, l1), fmaxf(l2, l3)), l4);
    const float e0 = __expf(l0 - m), e1 = __expf(l1 - m), e2 = __expf(l2 - m),
                e3 = __expf(l3 - m), e4 = __expf(l4 - m);
    const float rs = __builtin_amdgcn_rcpf(e0 + e1 + e2 + e3 + e4);
    prob_s[0][n] = e0 * rs; prob_s[1][n] = e1 * rs; prob_s[2][n] = e2 * rs;
    prob_s[3][n] = e3 * rs; prob_s[4][n] = e4 * rs;
  }
  __syncthreads();
  if (tid >= 96 && tid < 176) {
    out[(((size_t)b * P_ + (P_ - 1)) * 5 + sk) * T_ + t0 + sn] = prob_s[sk][sn];
  }
}

extern "C" void kernel_launch(void* const* d_in, const int* in_sizes, int n_in,
                              void* d_out, int out_size, void* d_ws, size_t ws_size,
                              hipStream_t stream) {
  const float* pf   = (const float*)d_in[0];
  const float* pc   = (const float*)d_in[1];
  const float* fc1w = (const float*)d_in[2];
  const float* fc1b = (const float*)d_in[3];
  const float* fc2w = (const float*)d_in[4];
  const float* fc2b = (const float*)d_in[5];
  const float* fc3w = (const float*)d_in[6];
  const float* fc3b = (const float*)d_in[7];
  const float* wih1 = (const float*)d_in[8];
  const float* whh1 = (const float*)d_in[9];
  const float* bih1 = (const float*)d_in[10];
  const float* bhh1 = (const float*)d_in[11];
  const float* wih2 = (const float*)d_in[12];
  const float* whh2 = (const float*)d_in[13];
  const float* bih2 = (const float*)d_in[14];
  const float* bhh2 = (const float*)d_in[15];
  const float* fcw  = (const float*)d_in[16];
  const float* fcb  = (const float*)d_in[17];
  float* out = (float*)d_out;

  char* wsp = (char*)d_ws;
  float* ctxg = (float*)wsp;                                     // 1,081,344 B
  const size_t CTXG_BYTES = (size_t)B_ * P_ * G_ * sizeof(float);
  f16x8* wfrag = (f16x8*)(wsp + CTXG_BYTES);                     // 73,728 B
  const size_t WFRAG_BYTES = (size_t)12 * 6 * 64 * 16;
  unsigned short* xg2 = (unsigned short*)(wsp + CTXG_BYTES + WFRAG_BYTES);  // ~138.5 MB

  ctx_kernel<<<22, 64, 0, stream>>>(pc, fc1w, fc1b, fc2w, fc2b, fc3w, fc3b,
                                    wih1, bih1, bhh1, ctxg);
  wfrag_kernel<<<18, 256, 0, stream>>>(wih1, wfrag);
  gemm_mfma<<<B_ * P_, 256, 0, stream>>>(pf, wfrag, ctxg, xg2);
  scan_mfma<<<N_ / 16, 256, 0, stream>>>(xg2, whh1, wih2, whh2,
                                         bih2, bhh2, fcw, fcb, out);
}

// Round 7
// 420.857 us; speedup vs baseline: 5.1572x; 2.1547x over previous
//
#include <hip/hip_runtime.h>
#include <hip/hip_bf16.h>
#include <cstdint>

#define P_ 88   // pitches (sequence length of the scan)
#define B_ 16   // batch
#define T_ 256  // timesteps (folded into batch N)
#define H_ 188  // per-pitch features
#define G_ 192  // 4*48 gates; also LSTM1 input size (188 feat + 4 ctx)
#define U_ 48   // LSTM units
#define N_ 4096 // B_*T_

typedef __attribute__((ext_vector_type(8))) short bf16x8;
typedef __attribute__((ext_vector_type(8))) _Float16 f16x8;
typedef __attribute__((ext_vector_type(4))) float f32x4;

__device__ __forceinline__ float sigf(float x) {
  return __builtin_amdgcn_rcpf(1.0f + __expf(-x));
}
__device__ __forceinline__ float tanh_f(float x) {
  return 1.0f - 2.0f * __builtin_amdgcn_rcpf(1.0f + __expf(2.0f * x));
}
__device__ __forceinline__ unsigned short f2bs(float v) {
  union { __hip_bfloat16 h; unsigned short s; } u;
  u.h = __float2bfloat16(v);
  return u.s;
}
__device__ __forceinline__ float bs2f(unsigned short s) {
  union { unsigned int u; float f; } x;
  x.u = ((unsigned int)s) << 16;
  return x.f;
}
__device__ __forceinline__ float hs2f(unsigned short s) {
  union { unsigned short u; _Float16 h; } x;
  x.u = s;
  return (float)x.h;
}
__device__ __forceinline__ unsigned short f2hs(float v) {
  union { _Float16 h; unsigned short s; } x;
  x.h = (_Float16)v;
  return x.s;
}

// ---------------------------------------------------------------------------
// Kernel 1: context MLP -> per-(b,p) gate bias vector
// ---------------------------------------------------------------------------
__global__ void ctx_kernel(const float* __restrict__ pc,
                           const float* __restrict__ fc1w, const float* __restrict__ fc1b,
                           const float* __restrict__ fc2w, const float* __restrict__ fc2b,
                           const float* __restrict__ fc3w, const float* __restrict__ fc3b,
                           const float* __restrict__ wih1,
                           const float* __restrict__ bih1, const float* __restrict__ bhh1,
                           float* __restrict__ ctxg) {
  int bp = blockIdx.x * 64 + threadIdx.x;
  if (bp >= B_ * P_) return;
  float p0 = pc[bp * 3 + 0], p1 = pc[bp * 3 + 1], p2 = pc[bp * 3 + 2];
  float x1[16], x2[16];
#pragma unroll
  for (int jj = 0; jj < 16; ++jj)
    x1[jj] = fmaxf(0.f, fc1w[jj * 3 + 0] * p0 + fc1w[jj * 3 + 1] * p1 + fc1w[jj * 3 + 2] * p2 + fc1b[jj]);
#pragma unroll
  for (int jj = 0; jj < 16; ++jj) {
    float s = fc2b[jj];
#pragma unroll
    for (int i = 0; i < 16; ++i) s += fc2w[jj * 16 + i] * x1[i];
    x2[jj] = fmaxf(0.f, s);
  }
  float ce[4];
#pragma unroll
  for (int jj = 0; jj < 4; ++jj) {
    float s = fc3b[jj];
#pragma unroll
    for (int i = 0; i < 16; ++i) s += fc3w[jj * 16 + i] * x2[i];
    ce[jj] = s;
  }
  float* op = ctxg + (size_t)bp * G_;
  for (int g = 0; g < G_; ++g) {
    const float* wr = wih1 + (size_t)g * G_ + H_;
    op[g] = bih1[g] + bhh1[g] + ce[0] * wr[0] + ce[1] * wr[1] + ce[2] * wr[2] + ce[3] * wr[3];
  }
}

// ---------------------------------------------------------------------------
// Kernel 1b: pack wih1 feature columns (k<188, pad to 192) into f16 MFMA
// B-fragment order: wfrag[(j*6+kc)*64 + l] (74 KB, L2-hot for all blocks).
// ---------------------------------------------------------------------------
__global__ __launch_bounds__(256) void wfrag_kernel(const float* __restrict__ wih1,
                                                    f16x8* __restrict__ wfrag) {
  const int idx = blockIdx.x * 256 + threadIdx.x;
  if (idx >= 12 * 6 * 64) return;
  const int l = idx & 63;
  const int kc = (idx >> 6) % 6;
  const int j = idx / 384;
  const int g = j * 16 + (l & 15);
  const int k0 = kc * 32 + (l >> 4) * 8;
  f16x8 v;
#pragma unroll
  for (int e = 0; e < 8; ++e) {
    const int k = k0 + e;
    const float wv = (k < H_) ? wih1[(size_t)g * G_ + k] : 0.f;
    v[e] = (_Float16)wv;
  }
  wfrag[idx] = v;
}

// ---------------------------------------------------------------------------
// Kernel 2: MFMA GEMM with LDS-staged A and LDS-repacked stores.
// Grid: 2816 blocks = (b,p) x 2 t-halves. 256 threads / 4 waves.
// Per K-chunk (32 k): float4-coalesced load of pf[32k x 128t] -> f16 hi/lo
// into transposed LDS [t][34] -> each lane's A-fragment = one b128 read.
// Wave w owns t rows w*32..w*32+31 (2 m-tiles); acc[2][12] f32x4.
// Epilogue: acc -> per-wave LDS repack -> uint4 (16B/lane) global stores.
// ---------------------------------------------------------------------------
__global__ __launch_bounds__(256, 3) void gemm_mfma(const float* __restrict__ pf,
                                                    const f16x8* __restrict__ wfrag,
                                                    const float* __restrict__ ctxg,
                                                    unsigned short* __restrict__ xg2) {
  const int bp = blockIdx.x >> 1, tb = blockIdx.x & 1;
  const int p = bp % P_, b = bp / P_;
  const int tid = threadIdx.x;
  const int w = tid >> 6, l = tid & 63;
  const int lj = l & 15, lq = l >> 4;

  __shared__ __align__(16) char ldsraw[49152];  // 48 KB: staging then epilogue
  _Float16(*Ahi)[34] = (_Float16(*)[34])ldsraw;             // [128][34] f16
  _Float16(*Alo)[34] = (_Float16(*)[34])(ldsraw + 8704);    // [128][34] f16

  float cg[12];
#pragma unroll
  for (int jn = 0; jn < 12; ++jn)
    cg[jn] = ctxg[(size_t)bp * G_ + jn * 16 + lj];

  f32x4 acc[2][12];
#pragma unroll
  for (int mt = 0; mt < 2; ++mt)
#pragma unroll
    for (int jn = 0; jn < 12; ++jn)
#pragma unroll
      for (int r = 0; r < 4; ++r) acc[mt][jn][r] = 0.f;

  const float* Ab = pf + (size_t)bp * H_ * T_ + tb * 128;
  const int kl = tid >> 5;         // 0..7  (k row within an 8-row group)
  const int t4 = (tid & 31) * 4;   // 0..124 (t within the 128-half)

  for (int kc = 0; kc < 6; ++kc) {
    __syncthreads();  // previous chunk's fragment reads complete
#pragma unroll
    for (int rr = 0; rr < 4; ++rr) {
      const int kk = rr * 8 + kl;       // 0..31 within chunk
      const int kg = kc * 32 + kk;
      float a0 = 0.f, a1 = 0.f, a2 = 0.f, a3 = 0.f;
      if (kg < H_) {
        const float4 v = *(const float4*)(Ab + (size_t)kg * T_ + t4);
        a0 = v.x; a1 = v.y; a2 = v.z; a3 = v.w;
      }
      const _Float16 h0 = (_Float16)a0, h1 = (_Float16)a1;
      const _Float16 h2 = (_Float16)a2, h3 = (_Float16)a3;
      Ahi[t4 + 0][kk] = h0; Alo[t4 + 0][kk] = (_Float16)(a0 - (float)h0);
      Ahi[t4 + 1][kk] = h1; Alo[t4 + 1][kk] = (_Float16)(a1 - (float)h1);
      Ahi[t4 + 2][kk] = h2; Alo[t4 + 2][kk] = (_Float16)(a2 - (float)h2);
      Ahi[t4 + 3][kk] = h3; Alo[t4 + 3][kk] = (_Float16)(a3 - (float)h3);
    }
    __syncthreads();
    const int trow = w * 32;
    const f16x8 ahi0 = *(const f16x8*)&Ahi[trow + lj][lq * 8];
    const f16x8 ahi1 = *(const f16x8*)&Ahi[trow + 16 + lj][lq * 8];
    const f16x8 alo0 = *(const f16x8*)&Alo[trow + lj][lq * 8];
    const f16x8 alo1 = *(const f16x8*)&Alo[trow + 16 + lj][lq * 8];
#pragma unroll
    for (int jn = 0; jn < 12; ++jn) {
      const f16x8 wf = wfrag[(jn * 6 + kc) * 64 + l];
      acc[0][jn] = __builtin_amdgcn_mfma_f32_16x16x32_f16(ahi0, wf, acc[0][jn], 0, 0, 0);
      acc[1][jn] = __builtin_amdgcn_mfma_f32_16x16x32_f16(ahi1, wf, acc[1][jn], 0, 0, 0);
      acc[0][jn] = __builtin_amdgcn_mfma_f32_16x16x32_f16(alo0, wf, acc[0][jn], 0, 0, 0);
      acc[1][jn] = __builtin_amdgcn_mfma_f32_16x16x32_f16(alo1, wf, acc[1][jn], 0, 0, 0);
    }
  }
  __syncthreads();  // staging region now free for epilogue reuse

  // ---- epilogue: + ctx bias, f16, repack via per-wave LDS, uint4 stores ----
  unsigned short* Cst = (unsigned short*)ldsraw + w * 6144;  // 12 KB per wave
#pragma unroll
  for (int mt = 0; mt < 2; ++mt)
#pragma unroll
    for (int jn = 0; jn < 12; ++jn)
#pragma unroll
      for (int r = 0; r < 4; ++r)
        Cst[mt * 3072 + jn * 256 + r * 64 + l] = f2hs(acc[mt][jn][r] + cg[jn]);
  // (wave-local LDS dependency; compiler inserts the lgkmcnt wait)
  const int nb0 = b * 16 + tb * 8 + w * 2;
  unsigned short* gb = xg2 + ((size_t)p * 256 + nb0) * 3072;
#pragma unroll
  for (int rr = 0; rr < 12; ++rr) {
    const uint4 v = *(const uint4*)(Cst + rr * 512 + l * 8);
    *(uint4*)(gb + rr * 512 + l * 8) = v;
  }
}

// ---------------------------------------------------------------------------
// Kernel 3: MFMA persistent scan (unchanged; reads f16 xg).
// ---------------------------------------------------------------------------
__global__ __launch_bounds__(256, 1) void scan_mfma(
    const unsigned short* __restrict__ xg2,
    const float* __restrict__ whh1, const float* __restrict__ wih2,
    const float* __restrict__ whh2, const float* __restrict__ bih2,
    const float* __restrict__ bhh2, const float* __restrict__ fcw,
    const float* __restrict__ fcb, float* __restrict__ out) {
  __shared__ __align__(16) short hh[16][104];   // h hi bits: cols 0-47 h1, 48-95 h2
  __shared__ __align__(16) short hl[16][104];   // h lo bits
  __shared__ __align__(16) float gs[16][196];   // gate staging (one layer at a time)
  __shared__ __align__(16) float h2f[16][52];   // h2 fp32 for fc_states
  __shared__ __align__(16) float fcws[5 * 48];
  __shared__ float logit_s[5][16];
  __shared__ float prob_s[5][16];

  const int tid = threadIdx.x;
  const int w = tid >> 6;   // wave 0..3
  const int l = tid & 63;
  const int lj = l & 15;    // A-row m / C col n within a 16-tile
  const int lq = l >> 4;    // quad
  const int n0 = blockIdx.x * 16;
  const int b = n0 >> 8, t0 = n0 & 255;

  // ---- persistent weight B-fragments (one-time gather) ----
  bf16x8 b1[3][2];
  bf16x8 b2f[3][3];
  float bias2r[3];
#pragma unroll
  for (int i = 0; i < 3; ++i) {
    const int j = w * 48 + i * 16 + lj;
    bias2r[i] = bih2[j] + bhh2[j];
#pragma unroll
    for (int kc = 0; kc < 2; ++kc)
#pragma unroll
      for (int e = 0; e < 8; ++e) {
        const int u = kc * 32 + lq * 8 + e;
        b1[i][kc][e] = (u < U_) ? (short)f2bs(whh1[j * U_ + u]) : (short)0;
      }
#pragma unroll
    for (int kc = 0; kc < 3; ++kc)
#pragma unroll
      for (int e = 0; e < 8; ++e) {
        const int u = kc * 32 + lq * 8 + e;
        b2f[i][kc][e] = (u < U_) ? (short)f2bs(wih2[j * U_ + u])
                                 : (short)f2bs(whh2[j * U_ + (u - U_)]);
      }
  }

  for (int e = tid; e < 16 * 104 / 2; e += 256) {
    ((unsigned int*)hh)[e] = 0u;
    ((unsigned int*)hl)[e] = 0u;
  }
  for (int e = tid; e < 5 * U_; e += 256) fcws[e] = fcw[e];

  int tn[3], tu[3];
  float c1r[3] = {0.f, 0.f, 0.f}, c2r[3] = {0.f, 0.f, 0.f};
#pragma unroll
  for (int s = 0; s < 3; ++s) {
    const int task = tid + 256 * s;
    tn[s] = task / U_;
    tu[s] = task % U_;
  }
  const bool fcth = tid < 80;
  const int fk = tid >> 4, fn = tid & 15;
  const float fcbr = fcth ? fcb[fk] : 0.f;
  const int sk = (tid - 96) >> 4, sn = (tid - 96) & 15;

  unsigned short xp[12];
  {
    const size_t pb = (size_t)blockIdx.x * 3072;
#pragma unroll
    for (int i = 0; i < 3; ++i)
#pragma unroll
      for (int r = 0; r < 4; ++r)
        xp[i * 4 + r] = xg2[pb + (size_t)((w * 3 + i) * 256 + r * 64 + l)];
  }
  const short* hhrow = &hh[lj][0];
  const short* hlrow = &hl[lj][0];
  __syncthreads();

  for (int p = 0; p < P_; ++p) {
    // ---- PHASE A: L1 MFMA (C init = xg) | fc_states logits for p-1 ----
    f32x4 c1f[3];
#pragma unroll
    for (int i = 0; i < 3; ++i)
#pragma unroll
      for (int r = 0; r < 4; ++r) c1f[i][r] = hs2f(xp[i * 4 + r]);
    {
      bf16x8 ah0 = *(const bf16x8*)(hhrow + lq * 8);
      bf16x8 ah1 = *(const bf16x8*)(hhrow + 32 + lq * 8);
      bf16x8 al0 = *(const bf16x8*)(hlrow + lq * 8);
      bf16x8 al1 = *(const bf16x8*)(hlrow + 32 + lq * 8);
#pragma unroll
      for (int i = 0; i < 3; ++i)
        c1f[i] = __builtin_amdgcn_mfma_f32_16x16x32_bf16(ah0, b1[i][0], c1f[i], 0, 0, 0);
#pragma unroll
      for (int i = 0; i < 3; ++i)
        c1f[i] = __builtin_amdgcn_mfma_f32_16x16x32_bf16(ah1, b1[i][1], c1f[i], 0, 0, 0);
#pragma unroll
      for (int i = 0; i < 3; ++i)
        c1f[i] = __builtin_amdgcn_mfma_f32_16x16x32_bf16(al0, b1[i][0], c1f[i], 0, 0, 0);
#pragma unroll
      for (int i = 0; i < 3; ++i)
        c1f[i] = __builtin_amdgcn_mfma_f32_16x16x32_bf16(al1, b1[i][1], c1f[i], 0, 0, 0);
    }
#pragma unroll
    for (int i = 0; i < 3; ++i)
#pragma unroll
      for (int r = 0; r < 4; ++r)
        gs[lq * 4 + r][w * 48 + i * 16 + lj] = c1f[i][r];
    if (p > 0 && fcth) {
      float a = fcbr;
#pragma unroll
      for (int uq = 0; uq < 12; ++uq) {
        f32x4 hv = *(const f32x4*)&h2f[fn][uq * 4];
        f32x4 wv = *(const f32x4*)&fcws[fk * 48 + uq * 4];
        a += hv[0] * wv[0] + hv[1] * wv[1] + hv[2] * wv[2] + hv[3] * wv[3];
      }
      logit_s[fk][fn] = a;
    }
    __syncthreads();
    // ---- PHASE B: L1 activations/h1 update | softmax for p-1 ----
#pragma unroll
    for (int s = 0; s < 3; ++s) {
      const int n = tn[s], u = tu[s];
      const float ig = gs[n][u], fg = gs[n][48 + u];
      const float gg = gs[n][96 + u], og = gs[n][144 + u];
      const float cc = sigf(fg) * c1r[s] + sigf(ig) * tanh_f(gg);
      c1r[s] = cc;
      const float h = sigf(og) * tanh_f(cc);
      const unsigned short hb = f2bs(h);
      hh[n][u] = (short)hb;
      hl[n][u] = (short)f2bs(h - bs2f(hb));
    }
    if (p > 0 && tid >= 192 && tid < 208) {
      const int n = tid - 192;
      const float l0 = logit_s[0][n], l1 = logit_s[1][n], l2 = logit_s[2][n],
                  l3 = logit_s[3][n], l4 = logit_s[4][n];
      const float m = fmaxf(fmaxf(fmaxf(l0, l1), fmaxf(l2, l3)), l4);
      const float e0 = __expf(l0 - m), e1 = __expf(l1 - m), e2 = __expf(l2 - m),
                  e3 = __expf(l3 - m), e4 = __expf(l4 - m);
      const float rs = __builtin_amdgcn_rcpf(e0 + e1 + e2 + e3 + e4);
      prob_s[0][n] = e0 * rs; prob_s[1][n] = e1 * rs; prob_s[2][n] = e2 * rs;
      prob_s[3][n] = e3 * rs; prob_s[4][n] = e4 * rs;
    }
    __syncthreads();
    // ---- PHASE C: L2 MFMA (+ xg prefetch p+1) | store p-1 ----
    if (p < P_ - 1) {
      const size_t pb = (size_t)((p + 1) * 256 + blockIdx.x) * 3072;
#pragma unroll
      for (int i = 0; i < 3; ++i)
#pragma unroll
        for (int r = 0; r < 4; ++r)
          xp[i * 4 + r] = xg2[pb + (size_t)((w * 3 + i) * 256 + r * 64 + l)];
    }
    f32x4 c2f[3];
#pragma unroll
    for (int i = 0; i < 3; ++i) {
      c2f[i][0] = bias2r[i]; c2f[i][1] = bias2r[i];
      c2f[i][2] = bias2r[i]; c2f[i][3] = bias2r[i];
    }
    {
      bf16x8 a0 = *(const bf16x8*)(hhrow + lq * 8);
      bf16x8 a1 = *(const bf16x8*)(hhrow + 32 + lq * 8);
      bf16x8 a2 = *(const bf16x8*)(hhrow + 64 + lq * 8);
      bf16x8 q0 = *(const bf16x8*)(hlrow + lq * 8);
      bf16x8 q1 = *(const bf16x8*)(hlrow + 32 + lq * 8);
      bf16x8 q2 = *(const bf16x8*)(hlrow + 64 + lq * 8);
#pragma unroll
      for (int i = 0; i < 3; ++i)
        c2f[i] = __builtin_amdgcn_mfma_f32_16x16x32_bf16(a0, b2f[i][0], c2f[i], 0, 0, 0);
#pragma unroll
      for (int i = 0; i < 3; ++i)
        c2f[i] = __builtin_amdgcn_mfma_f32_16x16x32_bf16(a1, b2f[i][1], c2f[i], 0, 0, 0);
#pragma unroll
      for (int i = 0; i < 3; ++i)
        c2f[i] = __builtin_amdgcn_mfma_f32_16x16x32_bf16(a2, b2f[i][2], c2f[i], 0, 0, 0);
#pragma unroll
      for (int i = 0; i < 3; ++i)
        c2f[i] = __builtin_amdgcn_mfma_f32_16x16x32_bf16(q0, b2f[i][0], c2f[i], 0, 0, 0);
#pragma unroll
      for (int i = 0; i < 3; ++i)
        c2f[i] = __builtin_amdgcn_mfma_f32_16x16x32_bf16(q1, b2f[i][1], c2f[i], 0, 0, 0);
#pragma unroll
      for (int i = 0; i < 3; ++i)
        c2f[i] = __builtin_amdgcn_mfma_f32_16x16x32_bf16(q2, b2f[i][2], c2f[i], 0, 0, 0);
    }
#pragma unroll
    for (int i = 0; i < 3; ++i)
#pragma unroll
      for (int r = 0; r < 4; ++r)
        gs[lq * 4 + r][w * 48 + i * 16 + lj] = c2f[i][r];
    if (p > 0 && tid >= 96 && tid < 176) {
      out[(((size_t)b * P_ + (p - 1)) * 5 + sk) * T_ + t0 + sn] = prob_s[sk][sn];
    }
    __syncthreads();
    // ---- PHASE D: L2 activations/h2 update ----
#pragma unroll
    for (int s = 0; s < 3; ++s) {
      const int n = tn[s], u = tu[s];
      const float ig = gs[n][u], fg = gs[n][48 + u];
      const float gg = gs[n][96 + u], og = gs[n][144 + u];
      const float cc = sigf(fg) * c2r[s] + sigf(ig) * tanh_f(gg);
      c2r[s] = cc;
      const float h = sigf(og) * tanh_f(cc);
      const unsigned short hb = f2bs(h);
      hh[n][48 + u] = (short)hb;
      hl[n][48 + u] = (short)f2bs(h - bs2f(hb));
      h2f[n][u] = h;
    }
    __syncthreads();
  }
  // ---- epilogue: fc/softmax/store for p = P_-1 ----
  if (fcth) {
    float a = fcbr;
#pragma unroll
    for (int uq = 0; uq < 12; ++uq) {
      f32x4 hv = *(const f32x4*)&h2f[fn][uq * 4];
      f32x4 wv = *(const f32x4*)&fcws[fk * 48 + uq * 4];
      a += hv[0] * wv[0] + hv[1] * wv[1] + hv[2] * wv[2] + hv[3] * wv[3];
    }
    logit_s[fk][fn] = a;
  }
  __syncthreads();
  if (tid >= 192 && tid < 208) {
    const int n = tid - 192;
    const float l0 = logit_s[0][n], l1 = logit_s[1][n], l2 = logit_s[2][n],
                l3 = logit_s[3][n], l4 = logit_s[4][n];
    const float m = fmaxf(fmaxf(fmaxf(l0, l1), fmaxf(l2, l3)), l4);
    const float e0 = __expf(l0 - m), e1 = __expf(l1 - m), e2 = __expf(l2 - m),
                e3 = __expf(l3 - m), e4 = __expf(l4 - m);
    const float rs = __builtin_amdgcn_rcpf(e0 + e1 + e2 + e3 + e4);
    prob_s[0][n] = e0 * rs; prob_s[1][n] = e1 * rs; prob_s[2][n] = e2 * rs;
    prob_s[3][n] = e3 * rs; prob_s[4][n] = e4 * rs;
  }
  __syncthreads();
  if (tid >= 96 && tid < 176) {
    out[(((size_t)b * P_ + (P_ - 1)) * 5 + sk) * T_ + t0 + sn] = prob_s[sk][sn];
  }
}

extern "C" void kernel_launch(void* const* d_in, const int* in_sizes, int n_in,
                              void* d_out, int out_size, void* d_ws, size_t ws_size,
                              hipStream_t stream) {
  const float* pf   = (const float*)d_in[0];
  const float* pc   = (const float*)d_in[1];
  const float* fc1w = (const float*)d_in[2];
  const float* fc1b = (const float*)d_in[3];
  const float* fc2w = (const float*)d_in[4];
  const float* fc2b = (const float*)d_in[5];
  const float* fc3w = (const float*)d_in[6];
  const float* fc3b = (const float*)d_in[7];
  const float* wih1 = (const float*)d_in[8];
  const float* whh1 = (const float*)d_in[9];
  const float* bih1 = (const float*)d_in[10];
  const float* bhh1 = (const float*)d_in[11];
  const float* wih2 = (const float*)d_in[12];
  const float* whh2 = (const float*)d_in[13];
  const float* bih2 = (const float*)d_in[14];
  const float* bhh2 = (const float*)d_in[15];
  const float* fcw  = (const float*)d_in[16];
  const float* fcb  = (const float*)d_in[17];
  float* out = (float*)d_out;

  char* wsp = (char*)d_ws;
  float* ctxg = (float*)wsp;                                     // 1,081,344 B
  const size_t CTXG_BYTES = (size_t)B_ * P_ * G_ * sizeof(float);
  f16x8* wfrag = (f16x8*)(wsp + CTXG_BYTES);                     // 73,728 B
  const size_t WFRAG_BYTES = (size_t)12 * 6 * 64 * 16;
  unsigned short* xg2 = (unsigned short*)(wsp + CTXG_BYTES + WFRAG_BYTES);  // ~138.5 MB

  ctx_kernel<<<22, 64, 0, stream>>>(pc, fc1w, fc1b, fc2w, fc2b, fc3w, fc3b,
                                    wih1, bih1, bhh1, ctxg);
  wfrag_kernel<<<18, 256, 0, stream>>>(wih1, wfrag);
  gemm_mfma<<<B_ * P_ * 2, 256, 0, stream>>>(pf, wfrag, ctxg, xg2);
  scan_mfma<<<N_ / 16, 256, 0, stream>>>(xg2, whh1, wih2, whh2,
                                         bih2, bhh2, fcw, fcb, out);
}